// Round 1
// baseline (4738.167 us; speedup 1.0000x reference)
//
#include <hip/hip_runtime.h>

#define NN 262144   // nodes
#define NE 4194304  // edges
#define NG 16384    // graphs
#define NC 26       // classes
#define F1 16
#define F2 32

// ---------------- kernels ----------------

// Count in-degree per dst node (4 edges per thread, vectorized idx load)
__global__ __launch_bounds__(256) void k_deg(const int* __restrict__ dst,
                                             int* __restrict__ degI) {
    int t = blockIdx.x * 256 + threadIdx.x;
    int base = t * 4;
    if (base < NE) {
        int4 d = ((const int4*)dst)[t];
        atomicAdd(&degI[d.x], 1);
        atomicAdd(&degI[d.y], 1);
        atomicAdd(&degI[d.z], 1);
        atomicAdd(&degI[d.w], 1);
    }
}

// dis[n] = rsqrt(deg + 2); also count nodes per graph
__global__ __launch_bounds__(256) void k_dis(const int* __restrict__ degI,
                                             float* __restrict__ dis,
                                             const int* __restrict__ batch,
                                             int* __restrict__ gcnt) {
    int n = blockIdx.x * 256 + threadIdx.x;
    if (n < NN) {
        dis[n] = rsqrtf((float)degI[n] + 2.0f);
        atomicAdd(&gcnt[batch[n]], 1);
    }
}

// Layer-1 edge aggregation on RAW x (3 floats) — linearity trick
__global__ __launch_bounds__(256) void k_agg1(const int* __restrict__ src,
                                              const int* __restrict__ dst,
                                              const float* __restrict__ dis,
                                              const float* __restrict__ x,
                                              float* __restrict__ ax) {
    int e = blockIdx.x * 256 + threadIdx.x;
    if (e < NE) {
        int s = src[e], d = dst[e];
        float nrm = dis[s] * dis[d];
        float x0 = x[s * 3 + 0], x1 = x[s * 3 + 1], x2 = x[s * 3 + 2];
        atomicAdd(&ax[d * 3 + 0], nrm * x0);
        atomicAdd(&ax[d * 3 + 1], nrm * x1);
        atomicAdd(&ax[d * 3 + 2], nrm * x2);
    }
}

// Layer-1 node update: h1 = relu((ax + 2*dis^2*x) @ W1 + b1)
__global__ __launch_bounds__(256) void k_h1(const float* __restrict__ ax,
                                            const float* __restrict__ x,
                                            const float* __restrict__ dis,
                                            const float* __restrict__ W1,
                                            const float* __restrict__ b1,
                                            float* __restrict__ h1) {
    int n = blockIdx.x * 256 + threadIdx.x;
    if (n >= NN) return;
    float ds = dis[n];
    float sw = 2.0f * ds * ds;
    float a0 = ax[n * 3 + 0] + sw * x[n * 3 + 0];
    float a1v = ax[n * 3 + 1] + sw * x[n * 3 + 1];
    float a2 = ax[n * 3 + 2] + sw * x[n * 3 + 2];
    float4* hr = (float4*)(h1 + (size_t)n * F1);
    #pragma unroll
    for (int q = 0; q < 4; ++q) {
        float4 v;
        float* vp = (float*)&v;
        #pragma unroll
        for (int j = 0; j < 4; ++j) {
            int col = q * 4 + j;
            float acc = b1[col];
            acc += a0 * W1[0 * F1 + col];
            acc += a1v * W1[1 * F1 + col];
            acc += a2 * W1[2 * F1 + col];
            vp[j] = fmaxf(acc, 0.0f);
        }
        hr[q] = v;
    }
}

// Layer-2 edge aggregation on h1 (16 floats) — linearity trick
__global__ __launch_bounds__(256) void k_agg2(const int* __restrict__ src,
                                              const int* __restrict__ dst,
                                              const float* __restrict__ dis,
                                              const float* __restrict__ h1,
                                              float* __restrict__ a1) {
    int e = blockIdx.x * 256 + threadIdx.x;
    if (e < NE) {
        int s = src[e], d = dst[e];
        float nrm = dis[s] * dis[d];
        const float4* hr = (const float4*)(h1 + (size_t)s * F1);
        float* ar = a1 + (size_t)d * F1;
        #pragma unroll
        for (int q = 0; q < 4; ++q) {
            float4 v = hr[q];
            atomicAdd(ar + q * 4 + 0, nrm * v.x);
            atomicAdd(ar + q * 4 + 1, nrm * v.y);
            atomicAdd(ar + q * 4 + 2, nrm * v.z);
            atomicAdd(ar + q * 4 + 3, nrm * v.w);
        }
    }
}

// Layer-2 node update + fused graph pooling (h2 never materialized):
// h2 = relu((a1 + 2*dis^2*h1) @ W2 + b2); gsum[batch[n]] += h2
__global__ __launch_bounds__(256) void k_h2pool(const float* __restrict__ a1,
                                                const float* __restrict__ h1,
                                                const float* __restrict__ dis,
                                                const float* __restrict__ W2,
                                                const float* __restrict__ b2,
                                                const int* __restrict__ batch,
                                                float* __restrict__ gsum) {
    __shared__ float sW2[F1 * F2];
    __shared__ float sb2[F2];
    for (int i = threadIdx.x; i < F1 * F2; i += 256) sW2[i] = W2[i];
    if (threadIdx.x < F2) sb2[threadIdx.x] = b2[threadIdx.x];
    __syncthreads();

    int n = blockIdx.x * 256 + threadIdx.x;
    if (n >= NN) return;
    float ds = dis[n];
    float sw = 2.0f * ds * ds;
    float av[F1];
    const float4* a1r = (const float4*)(a1 + (size_t)n * F1);
    const float4* h1r = (const float4*)(h1 + (size_t)n * F1);
    #pragma unroll
    for (int q = 0; q < 4; ++q) {
        float4 a = a1r[q];
        float4 h = h1r[q];
        av[q * 4 + 0] = a.x + sw * h.x;
        av[q * 4 + 1] = a.y + sw * h.y;
        av[q * 4 + 2] = a.z + sw * h.z;
        av[q * 4 + 3] = a.w + sw * h.w;
    }
    int g = batch[n];
    float* gr = gsum + (size_t)g * F2;
    #pragma unroll
    for (int j = 0; j < F2; ++j) {
        float acc = sb2[j];
        #pragma unroll
        for (int k = 0; k < F1; ++k) acc += av[k] * sW2[k * F2 + j];
        acc = fmaxf(acc, 0.0f);
        atomicAdd(gr + j, acc);
    }
}

// Final: out[g,c] = (gsum[g]/max(cnt,1)) @ Wl + bl
__global__ __launch_bounds__(256) void k_out(const float* __restrict__ gsum,
                                             const int* __restrict__ gcnt,
                                             const float* __restrict__ Wl,
                                             const float* __restrict__ bl,
                                             float* __restrict__ out) {
    int t = blockIdx.x * 256 + threadIdx.x;
    if (t >= NG * NC) return;
    int g = t / NC, c = t - g * NC;
    float inv = 1.0f / fmaxf((float)gcnt[g], 1.0f);
    const float* gr = gsum + (size_t)g * F2;
    float acc = bl[c];
    #pragma unroll
    for (int k = 0; k < F2; ++k) acc += gr[k] * Wl[k * NC + c];
    out[t] = acc * 1.0f + 0.0f;  // note: bias added before scaling? see below
}

// Correct version: pooled = gsum*inv first, THEN @Wl + bl. Do it properly:
__global__ __launch_bounds__(256) void k_out2(const float* __restrict__ gsum,
                                              const int* __restrict__ gcnt,
                                              const float* __restrict__ Wl,
                                              const float* __restrict__ bl,
                                              float* __restrict__ out) {
    int t = blockIdx.x * 256 + threadIdx.x;
    if (t >= NG * NC) return;
    int g = t / NC, c = t - g * NC;
    float inv = 1.0f / fmaxf((float)gcnt[g], 1.0f);
    const float* gr = gsum + (size_t)g * F2;
    float acc = 0.0f;
    #pragma unroll
    for (int k = 0; k < F2; ++k) acc += gr[k] * Wl[k * NC + c];
    out[t] = acc * inv + bl[c];
}

// ---------------- launcher ----------------

extern "C" void kernel_launch(void* const* d_in, const int* in_sizes, int n_in,
                              void* d_out, int out_size, void* d_ws, size_t ws_size,
                              hipStream_t stream) {
    const float* x    = (const float*)d_in[0];
    const int*   ei   = (const int*)d_in[1];
    const int*   src  = ei;
    const int*   dst  = ei + NE;
    const int*   batch= (const int*)d_in[2];
    const float* W1   = (const float*)d_in[3];
    const float* b1   = (const float*)d_in[4];
    const float* W2   = (const float*)d_in[5];
    const float* b2   = (const float*)d_in[6];
    const float* Wl   = (const float*)d_in[7];
    const float* bl   = (const float*)d_in[8];
    float* out = (float*)d_out;

    // workspace layout
    int*   degI = (int*)d_ws;                 // NN ints   (zeroed)
    int*   gcnt = degI + NN;                  // NG ints   (zeroed)
    float* ax   = (float*)(gcnt + NG);        // 3*NN      (zeroed)
    float* a1   = ax + 3 * (size_t)NN;        // 16*NN     (zeroed)
    float* gsum = a1 + (size_t)F1 * NN;       // 32*NG     (zeroed)
    float* dis  = gsum + (size_t)F2 * NG;     // NN
    float* h1   = dis + NN;                   // 16*NN

    size_t zero_elems = (size_t)NN + NG + 3 * (size_t)NN + (size_t)F1 * NN + (size_t)F2 * NG;
    hipMemsetAsync(d_ws, 0, zero_elems * sizeof(float), stream);

    k_deg<<<NE / 4 / 256, 256, 0, stream>>>(dst, degI);
    k_dis<<<(NN + 255) / 256, 256, 0, stream>>>(degI, dis, batch, gcnt);
    k_agg1<<<(NE + 255) / 256, 256, 0, stream>>>(src, dst, dis, x, ax);
    k_h1<<<(NN + 255) / 256, 256, 0, stream>>>(ax, x, dis, W1, b1, h1);
    k_agg2<<<(NE + 255) / 256, 256, 0, stream>>>(src, dst, dis, h1, a1);
    k_h2pool<<<(NN + 255) / 256, 256, 0, stream>>>(a1, h1, dis, W2, b2, batch, gsum);
    k_out2<<<(NG * NC + 255) / 256, 256, 0, stream>>>(gsum, gcnt, Wl, bl, out);
}

// Round 2
// 991.173 us; speedup vs baseline: 4.7804x; 4.7804x over previous
//
#include <hip/hip_runtime.h>

#define NN 262144   // nodes
#define NE 4194304  // edges (divisible by 1024)
#define NG 16384    // graphs
#define NC 26       // classes
#define F1 16
#define F2 32

// ---------- degree count (int atomics; 4 edges/thread) ----------
__global__ __launch_bounds__(256) void k_deg(const int* __restrict__ dst,
                                             int* __restrict__ degI) {
    int t = blockIdx.x * 256 + threadIdx.x;
    int4 d = ((const int4*)dst)[t];
    atomicAdd(&degI[d.x], 1);
    atomicAdd(&degI[d.y], 1);
    atomicAdd(&degI[d.z], 1);
    atomicAdd(&degI[d.w], 1);
}

// ---------- dis = rsqrt(deg+2); per-graph node counts ----------
__global__ __launch_bounds__(256) void k_dis(const int* __restrict__ degI,
                                             float* __restrict__ dis,
                                             const int* __restrict__ batch,
                                             int* __restrict__ gcnt) {
    int n = blockIdx.x * 256 + threadIdx.x;
    if (n < NN) {
        dis[n] = rsqrtf((float)degI[n] + 2.0f);
        atomicAdd(&gcnt[batch[n]], 1);
    }
}

// ---------- exclusive scan of degI -> rowptr (3 kernels) ----------
// scan1: 256 blocks x 256 threads, 4 elements/thread (1024/block)
__global__ __launch_bounds__(256) void k_scan1(const int* __restrict__ degI,
                                               int* __restrict__ rowptr,
                                               int* __restrict__ bsum) {
    __shared__ int s[256];
    int tid = threadIdx.x;
    int idx = blockIdx.x * 256 + tid;
    int4 v = ((const int4*)degI)[idx];
    int tsum = v.x + v.y + v.z + v.w;
    s[tid] = tsum;
    __syncthreads();
    #pragma unroll
    for (int off = 1; off < 256; off <<= 1) {
        int val = (tid >= off) ? s[tid - off] : 0;
        __syncthreads();
        if (tid >= off) s[tid] += val;
        __syncthreads();
    }
    int excl = s[tid] - tsum;   // exclusive prefix of this thread's chunk
    int base = idx * 4;
    rowptr[base + 0] = excl;
    rowptr[base + 1] = excl + v.x;
    rowptr[base + 2] = excl + v.x + v.y;
    rowptr[base + 3] = excl + v.x + v.y + v.z;
    if (tid == 255) bsum[blockIdx.x] = s[255];
}

// scan2: single block scans the 256 block sums in-place (-> exclusive)
__global__ __launch_bounds__(256) void k_scan2(int* __restrict__ bsum,
                                               int* __restrict__ rowptr) {
    __shared__ int s[256];
    int tid = threadIdx.x;
    int v = bsum[tid];
    s[tid] = v;
    __syncthreads();
    #pragma unroll
    for (int off = 1; off < 256; off <<= 1) {
        int val = (tid >= off) ? s[tid - off] : 0;
        __syncthreads();
        if (tid >= off) s[tid] += val;
        __syncthreads();
    }
    bsum[tid] = s[tid] - v;     // exclusive block offset
    if (tid == 0) rowptr[NN] = NE;
}

// scan3: add block offsets
__global__ __launch_bounds__(256) void k_scan3(int* __restrict__ rowptr,
                                               const int* __restrict__ bsum) {
    int i = blockIdx.x * 256 + threadIdx.x;   // i < NN always (grid exact)
    rowptr[i] += bsum[i >> 10];
}

// ---------- counting-sort scatter: csr_src[rowptr[d] + cursor] = src ----------
__global__ __launch_bounds__(256) void k_scatter(const int* __restrict__ src,
                                                 const int* __restrict__ dst,
                                                 const int* __restrict__ rowptr,
                                                 int* __restrict__ cnt,
                                                 int* __restrict__ csr_src) {
    int e = blockIdx.x * 256 + threadIdx.x;   // e < NE always (grid exact)
    int d = dst[e];
    int pos = rowptr[d] + atomicAdd(&cnt[d], 1);
    csr_src[pos] = src[e];
}

// ---------- layer 1: gather raw x (linearity) + fused 3->16 matmul + ReLU ----------
__global__ __launch_bounds__(256) void k_g1(const int* __restrict__ rowptr,
                                            const int* __restrict__ csr_src,
                                            const float* __restrict__ dis,
                                            const float* __restrict__ x,
                                            const float* __restrict__ W1,
                                            const float* __restrict__ b1,
                                            float* __restrict__ h1) {
    __shared__ float sW1[3 * F1];
    __shared__ float sb1[F1];
    if (threadIdx.x < 3 * F1) sW1[threadIdx.x] = W1[threadIdx.x];
    if (threadIdx.x < F1) sb1[threadIdx.x] = b1[threadIdx.x];
    __syncthreads();
    int n = blockIdx.x * 256 + threadIdx.x;   // grid exact: n < NN
    float dd = dis[n];
    int beg = rowptr[n], end = rowptr[n + 1];
    float a0 = 0.f, a1v = 0.f, a2 = 0.f;
    for (int e = beg; e < end; ++e) {
        int s_ = csr_src[e];
        float nrm = dd * dis[s_];
        a0  += nrm * x[3 * s_ + 0];
        a1v += nrm * x[3 * s_ + 1];
        a2  += nrm * x[3 * s_ + 2];
    }
    float sw = 2.0f * dd * dd;
    a0  += sw * x[3 * n + 0];
    a1v += sw * x[3 * n + 1];
    a2  += sw * x[3 * n + 2];
    float4* hr = (float4*)(h1 + (size_t)n * F1);
    #pragma unroll
    for (int qq = 0; qq < 4; ++qq) {
        float4 o;
        float* op = (float*)&o;
        #pragma unroll
        for (int j = 0; j < 4; ++j) {
            int col = qq * 4 + j;
            float acc = sb1[col];
            acc += a0  * sW1[0 * F1 + col];
            acc += a1v * sW1[1 * F1 + col];
            acc += a2  * sW1[2 * F1 + col];
            op[j] = fmaxf(acc, 0.0f);
        }
        hr[qq] = o;
    }
}

// ---------- layer 2: 4 threads/node gather h1 quads + fused 16->32 matmul
// + ReLU + graph pooling (h2 and a1 never materialized) ----------
__global__ __launch_bounds__(256) void k_g2pool(const int* __restrict__ rowptr,
                                                const int* __restrict__ csr_src,
                                                const float* __restrict__ dis,
                                                const float* __restrict__ h1,
                                                const float* __restrict__ W2,
                                                const float* __restrict__ b2,
                                                const int* __restrict__ batch,
                                                float* __restrict__ gsum) {
    __shared__ float sW2[F1 * F2];
    __shared__ float sb2[F2];
    for (int i = threadIdx.x; i < F1 * F2; i += 256) sW2[i] = W2[i];
    if (threadIdx.x < F2) sb2[threadIdx.x] = b2[threadIdx.x];
    __syncthreads();
    int t = blockIdx.x * 256 + threadIdx.x;   // grid exact: t < 4*NN
    int n = t >> 2;                            // node
    int q = t & 3;                             // feature quad (4 floats)
    int lane = threadIdx.x & 63;
    float dd = dis[n];
    int beg = rowptr[n], end = rowptr[n + 1];
    float ax = 0.f, ay = 0.f, az = 0.f, aw = 0.f;
    for (int e = beg; e < end; ++e) {
        int s_ = csr_src[e];
        float nrm = dd * dis[s_];
        float4 v = *(const float4*)(h1 + (size_t)s_ * F1 + q * 4);
        ax += nrm * v.x; ay += nrm * v.y; az += nrm * v.z; aw += nrm * v.w;
    }
    float sw = 2.0f * dd * dd;
    float4 hv = *(const float4*)(h1 + (size_t)n * F1 + q * 4);
    ax += sw * hv.x; ay += sw * hv.y; az += sw * hv.z; aw += sw * hv.w;

    // assemble the full 16-vector in every lane of the quad via shuffles
    int qbase = lane & ~3;
    float av[F1];
    #pragma unroll
    for (int k = 0; k < F1; ++k) {
        int kc = k & 3;
        float comp = (kc == 0) ? ax : (kc == 1) ? ay : (kc == 2) ? az : aw;
        av[k] = __shfl(comp, qbase + (k >> 2), 64);
    }

    // thread q computes output columns [8q, 8q+8): h2 = relu(av@W2+b2), pool
    int g = batch[n];
    float* gr = gsum + (size_t)g * F2 + q * 8;
    #pragma unroll
    for (int j0 = 0; j0 < 8; ++j0) {
        int j = q * 8 + j0;
        float acc = sb2[j];
        #pragma unroll
        for (int k = 0; k < F1; ++k) acc += av[k] * sW2[k * F2 + j];
        atomicAdd(gr + j0, fmaxf(acc, 0.0f));
    }
}

// ---------- head: out[g,c] = (gsum[g]/max(cnt,1)) @ Wl + bl ----------
__global__ __launch_bounds__(256) void k_out2(const float* __restrict__ gsum,
                                              const int* __restrict__ gcnt,
                                              const float* __restrict__ Wl,
                                              const float* __restrict__ bl,
                                              float* __restrict__ out) {
    int t = blockIdx.x * 256 + threadIdx.x;
    if (t >= NG * NC) return;
    int g = t / NC, c = t - g * NC;
    float inv = 1.0f / fmaxf((float)gcnt[g], 1.0f);
    const float* gr = gsum + (size_t)g * F2;
    float acc = 0.0f;
    #pragma unroll
    for (int k = 0; k < F2; ++k) acc += gr[k] * Wl[k * NC + c];
    out[t] = acc * inv + bl[c];
}

// ---------------- launcher ----------------
extern "C" void kernel_launch(void* const* d_in, const int* in_sizes, int n_in,
                              void* d_out, int out_size, void* d_ws, size_t ws_size,
                              hipStream_t stream) {
    const float* x    = (const float*)d_in[0];
    const int*   ei   = (const int*)d_in[1];
    const int*   src  = ei;
    const int*   dst  = ei + NE;
    const int*   batch= (const int*)d_in[2];
    const float* W1   = (const float*)d_in[3];
    const float* b1   = (const float*)d_in[4];
    const float* W2   = (const float*)d_in[5];
    const float* b2   = (const float*)d_in[6];
    const float* Wl   = (const float*)d_in[7];
    const float* bl   = (const float*)d_in[8];
    float* out = (float*)d_out;

    // workspace layout (all offsets 16B-aligned)
    int*   degI    = (int*)d_ws;                  // NN      (zeroed)
    int*   cnt     = degI + NN;                   // NN      (zeroed)
    int*   gcnt    = cnt + NN;                    // NG      (zeroed)
    float* gsum    = (float*)(gcnt + NG);         // 32*NG   (zeroed)
    int*   rowptr  = (int*)(gsum + (size_t)F2 * NG); // NN+1 (pad to NN+4)
    int*   bsum    = rowptr + NN + 4;             // 256
    float* dis     = (float*)(bsum + 256);        // NN
    int*   csr_src = (int*)(dis + NN);            // NE
    float* h1      = (float*)(csr_src + NE);      // 16*NN

    size_t zero_elems = 2 * (size_t)NN + (size_t)NG + (size_t)F2 * NG;
    hipMemsetAsync(d_ws, 0, zero_elems * sizeof(int), stream);

    k_deg    <<<NE / 4 / 256, 256, 0, stream>>>(dst, degI);
    k_dis    <<<NN / 256, 256, 0, stream>>>(degI, dis, batch, gcnt);
    k_scan1  <<<NN / 1024, 256, 0, stream>>>(degI, rowptr, bsum);
    k_scan2  <<<1, 256, 0, stream>>>(bsum, rowptr);
    k_scan3  <<<NN / 256, 256, 0, stream>>>(rowptr, bsum);
    k_scatter<<<NE / 256, 256, 0, stream>>>(src, dst, rowptr, cnt, csr_src);
    k_g1     <<<NN / 256, 256, 0, stream>>>(rowptr, csr_src, dis, x, W1, b1, h1);
    k_g2pool <<<NN * 4 / 256, 256, 0, stream>>>(rowptr, csr_src, dis, h1, W2, b2, batch, gsum);
    k_out2   <<<(NG * NC + 255) / 256, 256, 0, stream>>>(gsum, gcnt, Wl, bl, out);
}

// Round 3
// 626.331 us; speedup vs baseline: 7.5650x; 1.5825x over previous
//
#include <hip/hip_runtime.h>

#define NN 262144   // nodes
#define NE 4194304  // edges (divisible by 1024)
#define NG 16384    // graphs
#define NC 26       // classes
#define F1 16
#define F2 32

// ---------- degree count (int atomics; 4 edges/thread) ----------
__global__ __launch_bounds__(256) void k_deg(const int* __restrict__ dst,
                                             int* __restrict__ degI) {
    int t = blockIdx.x * 256 + threadIdx.x;
    int4 d = ((const int4*)dst)[t];
    atomicAdd(&degI[d.x], 1);
    atomicAdd(&degI[d.y], 1);
    atomicAdd(&degI[d.z], 1);
    atomicAdd(&degI[d.w], 1);
}

// ---------- dis = rsqrt(deg+2); per-graph node counts ----------
__global__ __launch_bounds__(256) void k_dis(const int* __restrict__ degI,
                                             float* __restrict__ dis,
                                             const int* __restrict__ batch,
                                             int* __restrict__ gcnt) {
    int n = blockIdx.x * 256 + threadIdx.x;
    if (n < NN) {
        dis[n] = rsqrtf((float)degI[n] + 2.0f);
        atomicAdd(&gcnt[batch[n]], 1);
    }
}

// ---------- exclusive scan of degI -> rowptr (3 kernels) ----------
__global__ __launch_bounds__(256) void k_scan1(const int* __restrict__ degI,
                                               int* __restrict__ rowptr,
                                               int* __restrict__ bsum) {
    __shared__ int s[256];
    int tid = threadIdx.x;
    int idx = blockIdx.x * 256 + tid;
    int4 v = ((const int4*)degI)[idx];
    int tsum = v.x + v.y + v.z + v.w;
    s[tid] = tsum;
    __syncthreads();
    #pragma unroll
    for (int off = 1; off < 256; off <<= 1) {
        int val = (tid >= off) ? s[tid - off] : 0;
        __syncthreads();
        if (tid >= off) s[tid] += val;
        __syncthreads();
    }
    int excl = s[tid] - tsum;
    int base = idx * 4;
    rowptr[base + 0] = excl;
    rowptr[base + 1] = excl + v.x;
    rowptr[base + 2] = excl + v.x + v.y;
    rowptr[base + 3] = excl + v.x + v.y + v.z;
    if (tid == 255) bsum[blockIdx.x] = s[255];
}

__global__ __launch_bounds__(256) void k_scan2(int* __restrict__ bsum,
                                               int* __restrict__ rowptr) {
    __shared__ int s[256];
    int tid = threadIdx.x;
    int v = bsum[tid];
    s[tid] = v;
    __syncthreads();
    #pragma unroll
    for (int off = 1; off < 256; off <<= 1) {
        int val = (tid >= off) ? s[tid - off] : 0;
        __syncthreads();
        if (tid >= off) s[tid] += val;
        __syncthreads();
    }
    bsum[tid] = s[tid] - v;
    if (tid == 0) rowptr[NN] = NE;
}

__global__ __launch_bounds__(256) void k_scan3(int* __restrict__ rowptr,
                                               const int* __restrict__ bsum) {
    int i = blockIdx.x * 256 + threadIdx.x;
    rowptr[i] += bsum[i >> 10];
}

// ---------- counting-sort scatter ----------
__global__ __launch_bounds__(256) void k_scatter(const int* __restrict__ src,
                                                 const int* __restrict__ dst,
                                                 const int* __restrict__ rowptr,
                                                 int* __restrict__ cnt,
                                                 int* __restrict__ csr_src) {
    int e = blockIdx.x * 256 + threadIdx.x;
    int d = dst[e];
    int pos = rowptr[d] + atomicAdd(&cnt[d], 1);
    csr_src[pos] = src[e];
}

// ---------- layer 1: gather raw x + fused 3->16 matmul + ReLU (4x unroll) ----------
__global__ __launch_bounds__(256) void k_g1(const int* __restrict__ rowptr,
                                            const int* __restrict__ csr_src,
                                            const float* __restrict__ dis,
                                            const float* __restrict__ x,
                                            const float* __restrict__ W1,
                                            const float* __restrict__ b1,
                                            float* __restrict__ h1) {
    __shared__ float sW1[3 * F1];
    __shared__ float sb1[F1];
    if (threadIdx.x < 3 * F1) sW1[threadIdx.x] = W1[threadIdx.x];
    if (threadIdx.x < F1) sb1[threadIdx.x] = b1[threadIdx.x];
    __syncthreads();
    int n = blockIdx.x * 256 + threadIdx.x;
    float dd = dis[n];
    int beg = rowptr[n], end = rowptr[n + 1];
    float a0 = 0.f, a1v = 0.f, a2 = 0.f;
    int e = beg;
    for (; e + 3 < end; e += 4) {
        int s0 = csr_src[e], s1 = csr_src[e + 1], s2 = csr_src[e + 2], s3 = csr_src[e + 3];
        float m0 = dd * dis[s0], m1 = dd * dis[s1], m2 = dd * dis[s2], m3 = dd * dis[s3];
        float x00 = x[3*s0], x01 = x[3*s0+1], x02 = x[3*s0+2];
        float x10 = x[3*s1], x11 = x[3*s1+1], x12 = x[3*s1+2];
        float x20 = x[3*s2], x21 = x[3*s2+1], x22 = x[3*s2+2];
        float x30 = x[3*s3], x31 = x[3*s3+1], x32 = x[3*s3+2];
        a0  += m0*x00 + m1*x10 + m2*x20 + m3*x30;
        a1v += m0*x01 + m1*x11 + m2*x21 + m3*x31;
        a2  += m0*x02 + m1*x12 + m2*x22 + m3*x32;
    }
    for (; e < end; ++e) {
        int s_ = csr_src[e];
        float nrm = dd * dis[s_];
        a0  += nrm * x[3*s_ + 0];
        a1v += nrm * x[3*s_ + 1];
        a2  += nrm * x[3*s_ + 2];
    }
    float sw = 2.0f * dd * dd;
    a0  += sw * x[3*n + 0];
    a1v += sw * x[3*n + 1];
    a2  += sw * x[3*n + 2];
    float4* hr = (float4*)(h1 + (size_t)n * F1);
    #pragma unroll
    for (int qq = 0; qq < 4; ++qq) {
        float4 o;
        float* op = (float*)&o;
        #pragma unroll
        for (int j = 0; j < 4; ++j) {
            int col = qq * 4 + j;
            float acc = sb1[col];
            acc += a0  * sW1[0 * F1 + col];
            acc += a1v * sW1[1 * F1 + col];
            acc += a2  * sW1[2 * F1 + col];
            op[j] = fmaxf(acc, 0.0f);
        }
        hr[qq] = o;
    }
}

// ---------- layer 2: quad-gather + fused matmul + ReLU + SEGMENTED-SCAN pooling ----------
// 4 threads/node; wave = 16 consecutive nodes x 4 quads. batch is sorted, so
// pool via wave segmented scan over node slots; only segment-end lanes do atomics
// (~1M atomics instead of 8.4M).
__global__ __launch_bounds__(256) void k_h2seg(const int* __restrict__ rowptr,
                                               const int* __restrict__ csr_src,
                                               const float* __restrict__ dis,
                                               const float* __restrict__ h1,
                                               const float* __restrict__ W2,
                                               const float* __restrict__ b2,
                                               const int* __restrict__ batch,
                                               float* __restrict__ gsum) {
    __shared__ float sW2[F1 * F2];
    __shared__ float sb2[F2];
    for (int i = threadIdx.x; i < F1 * F2; i += 256) sW2[i] = W2[i];
    if (threadIdx.x < F2) sb2[threadIdx.x] = b2[threadIdx.x];
    __syncthreads();
    int t = blockIdx.x * 256 + threadIdx.x;   // grid exact: t < 4*NN
    int n = t >> 2;                           // node
    int q = t & 3;                            // feature quad
    int lane = threadIdx.x & 63;
    int islot = lane >> 2;                    // node slot within wave (0..15)
    float dd = dis[n];
    int beg = rowptr[n], end = rowptr[n + 1];
    float ax = 0.f, ay = 0.f, az = 0.f, aw = 0.f;
    int e = beg;
    for (; e + 3 < end; e += 4) {
        int s0 = csr_src[e], s1 = csr_src[e+1], s2 = csr_src[e+2], s3 = csr_src[e+3];
        float m0 = dd * dis[s0], m1 = dd * dis[s1], m2 = dd * dis[s2], m3 = dd * dis[s3];
        float4 v0 = *(const float4*)(h1 + (size_t)s0 * F1 + q * 4);
        float4 v1 = *(const float4*)(h1 + (size_t)s1 * F1 + q * 4);
        float4 v2 = *(const float4*)(h1 + (size_t)s2 * F1 + q * 4);
        float4 v3 = *(const float4*)(h1 + (size_t)s3 * F1 + q * 4);
        ax += m0*v0.x + m1*v1.x + m2*v2.x + m3*v3.x;
        ay += m0*v0.y + m1*v1.y + m2*v2.y + m3*v3.y;
        az += m0*v0.z + m1*v1.z + m2*v2.z + m3*v3.z;
        aw += m0*v0.w + m1*v1.w + m2*v2.w + m3*v3.w;
    }
    for (; e < end; ++e) {
        int s_ = csr_src[e];
        float nrm = dd * dis[s_];
        float4 v = *(const float4*)(h1 + (size_t)s_ * F1 + q * 4);
        ax += nrm * v.x; ay += nrm * v.y; az += nrm * v.z; aw += nrm * v.w;
    }
    float sw = 2.0f * dd * dd;
    float4 hv4 = *(const float4*)(h1 + (size_t)n * F1 + q * 4);
    ax += sw * hv4.x; ay += sw * hv4.y; az += sw * hv4.z; aw += sw * hv4.w;

    // assemble full 16-vector in each lane of the quad
    int qbase = lane & ~3;
    float av[F1];
    #pragma unroll
    for (int k = 0; k < F1; ++k) {
        int kc = k & 3;
        float comp = (kc == 0) ? ax : (kc == 1) ? ay : (kc == 2) ? az : aw;
        av[k] = __shfl(comp, qbase + (k >> 2), 64);
    }

    // h2 slice: thread q computes output columns [8q, 8q+8)
    float hv[8];
    #pragma unroll
    for (int j0 = 0; j0 < 8; ++j0) {
        int j = q * 8 + j0;
        float acc = sb2[j];
        #pragma unroll
        for (int k = 0; k < F1; ++k) acc += av[k] * sW2[k * F2 + j];
        hv[j0] = fmaxf(acc, 0.0f);
    }

    // wave segmented inclusive scan over node slots (stride-4 lanes), seg = graph
    int g = batch[n];
    #pragma unroll
    for (int d_ = 1; d_ < 16; d_ <<= 1) {
        int sl = lane - 4 * d_;
        int gs = __shfl(g, sl, 64);       // garbage when islot<d_, guarded below
        #pragma unroll
        for (int j0 = 0; j0 < 8; ++j0) {
            float o = __shfl(hv[j0], sl, 64);
            if (islot >= d_ && gs == g) hv[j0] += o;
        }
    }
    int gn = __shfl(g, lane + 4, 64);     // wraps when islot==15, guarded
    bool endseg = (islot == 15) || (gn != g);
    if (endseg) {
        float* gr = gsum + (size_t)g * F2 + q * 8;
        #pragma unroll
        for (int j0 = 0; j0 < 8; ++j0) atomicAdd(gr + j0, hv[j0]);
    }
}

// ---------- head ----------
__global__ __launch_bounds__(256) void k_out2(const float* __restrict__ gsum,
                                              const int* __restrict__ gcnt,
                                              const float* __restrict__ Wl,
                                              const float* __restrict__ bl,
                                              float* __restrict__ out) {
    int t = blockIdx.x * 256 + threadIdx.x;
    if (t >= NG * NC) return;
    int g = t / NC, c = t - g * NC;
    float inv = 1.0f / fmaxf((float)gcnt[g], 1.0f);
    const float* gr = gsum + (size_t)g * F2;
    float acc = 0.0f;
    #pragma unroll
    for (int k = 0; k < F2; ++k) acc += gr[k] * Wl[k * NC + c];
    out[t] = acc * inv + bl[c];
}

// ---------------- launcher ----------------
extern "C" void kernel_launch(void* const* d_in, const int* in_sizes, int n_in,
                              void* d_out, int out_size, void* d_ws, size_t ws_size,
                              hipStream_t stream) {
    const float* x    = (const float*)d_in[0];
    const int*   ei   = (const int*)d_in[1];
    const int*   src  = ei;
    const int*   dst  = ei + NE;
    const int*   batch= (const int*)d_in[2];
    const float* W1   = (const float*)d_in[3];
    const float* b1   = (const float*)d_in[4];
    const float* W2   = (const float*)d_in[5];
    const float* b2   = (const float*)d_in[6];
    const float* Wl   = (const float*)d_in[7];
    const float* bl   = (const float*)d_in[8];
    float* out = (float*)d_out;

    // workspace layout
    int*   degI    = (int*)d_ws;                     // NN      (zeroed)
    int*   cnt     = degI + NN;                      // NN      (zeroed)
    int*   gcnt    = cnt + NN;                       // NG      (zeroed)
    float* gsum    = (float*)(gcnt + NG);            // 32*NG   (zeroed)
    int*   rowptr  = (int*)(gsum + (size_t)F2 * NG); // NN+4
    int*   bsum    = rowptr + NN + 4;                // 256
    float* dis     = (float*)(bsum + 256);           // NN
    int*   csr_src = (int*)(dis + NN);               // NE
    float* h1      = (float*)(csr_src + NE);         // 16*NN

    size_t zero_elems = 2 * (size_t)NN + (size_t)NG + (size_t)F2 * NG;
    hipMemsetAsync(d_ws, 0, zero_elems * sizeof(int), stream);

    k_deg    <<<NE / 4 / 256, 256, 0, stream>>>(dst, degI);
    k_dis    <<<NN / 256, 256, 0, stream>>>(degI, dis, batch, gcnt);
    k_scan1  <<<NN / 1024, 256, 0, stream>>>(degI, rowptr, bsum);
    k_scan2  <<<1, 256, 0, stream>>>(bsum, rowptr);
    k_scan3  <<<NN / 256, 256, 0, stream>>>(rowptr, bsum);
    k_scatter<<<NE / 256, 256, 0, stream>>>(src, dst, rowptr, cnt, csr_src);
    k_g1     <<<NN / 256, 256, 0, stream>>>(rowptr, csr_src, dis, x, W1, b1, h1);
    k_h2seg  <<<NN * 4 / 256, 256, 0, stream>>>(rowptr, csr_src, dis, h1, W2, b2, batch, gsum);
    k_out2   <<<(NG * NC + 255) / 256, 256, 0, stream>>>(gsum, gcnt, Wl, bl, out);
}

// Round 4
// 437.343 us; speedup vs baseline: 10.8340x; 1.4321x over previous
//
#include <hip/hip_runtime.h>

#define NN 262144   // nodes
#define NE 4194304  // edges (divisible by 16384)
#define NG 16384    // graphs
#define NC 26       // classes
#define F1 16
#define F2 32
#define NB 256      // dst buckets (1024 nodes each)
#define BINCH 16384 // edges per k_bin block

// ---------- degree count (int atomics; 4 edges/thread) ----------
__global__ __launch_bounds__(256) void k_deg(const int* __restrict__ dst,
                                             int* __restrict__ degI) {
    int t = blockIdx.x * 256 + threadIdx.x;
    int4 d = ((const int4*)dst)[t];
    atomicAdd(&degI[d.x], 1);
    atomicAdd(&degI[d.y], 1);
    atomicAdd(&degI[d.z], 1);
    atomicAdd(&degI[d.w], 1);
}

// ---------- dis = rsqrt(deg+2); per-graph node counts ----------
__global__ __launch_bounds__(256) void k_dis(const int* __restrict__ degI,
                                             float* __restrict__ dis,
                                             const int* __restrict__ batch,
                                             int* __restrict__ gcnt) {
    int n = blockIdx.x * 256 + threadIdx.x;
    if (n < NN) {
        dis[n] = rsqrtf((float)degI[n] + 2.0f);
        atomicAdd(&gcnt[batch[n]], 1);
    }
}

// ---------- exclusive scan of degI -> rowptr (3 kernels) ----------
__global__ __launch_bounds__(256) void k_scan1(const int* __restrict__ degI,
                                               int* __restrict__ rowptr,
                                               int* __restrict__ bsum) {
    __shared__ int s[256];
    int tid = threadIdx.x;
    int idx = blockIdx.x * 256 + tid;
    int4 v = ((const int4*)degI)[idx];
    int tsum = v.x + v.y + v.z + v.w;
    s[tid] = tsum;
    __syncthreads();
    #pragma unroll
    for (int off = 1; off < 256; off <<= 1) {
        int val = (tid >= off) ? s[tid - off] : 0;
        __syncthreads();
        if (tid >= off) s[tid] += val;
        __syncthreads();
    }
    int excl = s[tid] - tsum;
    int base = idx * 4;
    rowptr[base + 0] = excl;
    rowptr[base + 1] = excl + v.x;
    rowptr[base + 2] = excl + v.x + v.y;
    rowptr[base + 3] = excl + v.x + v.y + v.z;
    if (tid == 255) bsum[blockIdx.x] = s[255];
}

__global__ __launch_bounds__(256) void k_scan2(int* __restrict__ bsum,
                                               int* __restrict__ rowptr) {
    __shared__ int s[256];
    int tid = threadIdx.x;
    int v = bsum[tid];
    s[tid] = v;
    __syncthreads();
    #pragma unroll
    for (int off = 1; off < 256; off <<= 1) {
        int val = (tid >= off) ? s[tid - off] : 0;
        __syncthreads();
        if (tid >= off) s[tid] += val;
        __syncthreads();
    }
    bsum[tid] = s[tid] - v;
    if (tid == 0) rowptr[NN] = NE;
}

__global__ __launch_bounds__(256) void k_scan3(int* __restrict__ rowptr,
                                               const int* __restrict__ bsum) {
    int i = blockIdx.x * 256 + threadIdx.x;
    rowptr[i] += bsum[i >> 10];
}

// ---------- bucket bases: gcur[b] = rowptr[b*1024] ----------
__global__ __launch_bounds__(256) void k_bbase(const int* __restrict__ rowptr,
                                               int* __restrict__ gcur) {
    int b = threadIdx.x;
    gcur[b] = rowptr[b << 10];
}

// ---------- multisplit binning: ebuf bucket-contiguous, packed (src<<10|dl) ----------
__global__ __launch_bounds__(512) void k_bin(const int* __restrict__ src,
                                             const int* __restrict__ dst,
                                             int* __restrict__ gcur,
                                             int* __restrict__ ebuf) {
    __shared__ int hist[NB];
    __shared__ int base[NB];
    int tid = threadIdx.x;
    if (tid < NB) hist[tid] = 0;
    __syncthreads();
    int e0 = blockIdx.x * BINCH;
    const int4* d4 = (const int4*)(dst + e0);
    const int4* s4 = (const int4*)(src + e0);
    #pragma unroll
    for (int k = 0; k < BINCH / 512 / 4; ++k) {   // 8 iters
        int4 d = d4[tid + k * 512];
        atomicAdd(&hist[d.x >> 10], 1);
        atomicAdd(&hist[d.y >> 10], 1);
        atomicAdd(&hist[d.z >> 10], 1);
        atomicAdd(&hist[d.w >> 10], 1);
    }
    __syncthreads();
    if (tid < NB) {
        base[tid] = atomicAdd(&gcur[tid], hist[tid]);
        hist[tid] = 0;
    }
    __syncthreads();
    #pragma unroll
    for (int k = 0; k < BINCH / 512 / 4; ++k) {
        int4 d = d4[tid + k * 512];
        int4 s = s4[tid + k * 512];
        int b, pos;
        b = d.x >> 10; pos = base[b] + atomicAdd(&hist[b], 1); ebuf[pos] = (s.x << 10) | (d.x & 1023);
        b = d.y >> 10; pos = base[b] + atomicAdd(&hist[b], 1); ebuf[pos] = (s.y << 10) | (d.y & 1023);
        b = d.z >> 10; pos = base[b] + atomicAdd(&hist[b], 1); ebuf[pos] = (s.z << 10) | (d.z & 1023);
        b = d.w >> 10; pos = base[b] + atomicAdd(&hist[b], 1); ebuf[pos] = (s.w << 10) | (d.w & 1023);
    }
}

// ---------- per-bucket CSR scatter: LDS cursors, L2-resident writes ----------
__global__ __launch_bounds__(512) void k_scatter2(const int* __restrict__ rowptr,
                                                  const int* __restrict__ ebuf,
                                                  int* __restrict__ csr_src) {
    __shared__ int srow[1024];
    __shared__ int scur[1024];
    __shared__ int sEnd;
    int tid = threadIdx.x;
    int n0 = blockIdx.x << 10;
    for (int i = tid; i < 1024; i += 512) { srow[i] = rowptr[n0 + i]; scur[i] = 0; }
    if (tid == 0) sEnd = rowptr[n0 + 1024];
    __syncthreads();
    int beg = srow[0], end = sEnd;
    for (int i = beg + tid; i < end; i += 512) {
        unsigned p = (unsigned)ebuf[i];
        int dl = p & 1023;
        int pos = srow[dl] + atomicAdd(&scur[dl], 1);
        csr_src[pos] = (int)(p >> 10);
    }
}

// ---------- layer 1: gather raw x + fused 3->16 matmul + ReLU (4x unroll) ----------
__global__ __launch_bounds__(256) void k_g1(const int* __restrict__ rowptr,
                                            const int* __restrict__ csr_src,
                                            const float* __restrict__ dis,
                                            const float* __restrict__ x,
                                            const float* __restrict__ W1,
                                            const float* __restrict__ b1,
                                            float* __restrict__ h1) {
    __shared__ float sW1[3 * F1];
    __shared__ float sb1[F1];
    if (threadIdx.x < 3 * F1) sW1[threadIdx.x] = W1[threadIdx.x];
    if (threadIdx.x < F1) sb1[threadIdx.x] = b1[threadIdx.x];
    __syncthreads();
    int n = blockIdx.x * 256 + threadIdx.x;
    float dd = dis[n];
    int beg = rowptr[n], end = rowptr[n + 1];
    float a0 = 0.f, a1v = 0.f, a2 = 0.f;
    int e = beg;
    for (; e + 3 < end; e += 4) {
        int s0 = csr_src[e], s1 = csr_src[e + 1], s2 = csr_src[e + 2], s3 = csr_src[e + 3];
        float m0 = dd * dis[s0], m1 = dd * dis[s1], m2 = dd * dis[s2], m3 = dd * dis[s3];
        float x00 = x[3*s0], x01 = x[3*s0+1], x02 = x[3*s0+2];
        float x10 = x[3*s1], x11 = x[3*s1+1], x12 = x[3*s1+2];
        float x20 = x[3*s2], x21 = x[3*s2+1], x22 = x[3*s2+2];
        float x30 = x[3*s3], x31 = x[3*s3+1], x32 = x[3*s3+2];
        a0  += m0*x00 + m1*x10 + m2*x20 + m3*x30;
        a1v += m0*x01 + m1*x11 + m2*x21 + m3*x31;
        a2  += m0*x02 + m1*x12 + m2*x22 + m3*x32;
    }
    for (; e < end; ++e) {
        int s_ = csr_src[e];
        float nrm = dd * dis[s_];
        a0  += nrm * x[3*s_ + 0];
        a1v += nrm * x[3*s_ + 1];
        a2  += nrm * x[3*s_ + 2];
    }
    float sw = 2.0f * dd * dd;
    a0  += sw * x[3*n + 0];
    a1v += sw * x[3*n + 1];
    a2  += sw * x[3*n + 2];
    float4* hr = (float4*)(h1 + (size_t)n * F1);
    #pragma unroll
    for (int qq = 0; qq < 4; ++qq) {
        float4 o;
        float* op = (float*)&o;
        #pragma unroll
        for (int j = 0; j < 4; ++j) {
            int col = qq * 4 + j;
            float acc = sb1[col];
            acc += a0  * sW1[0 * F1 + col];
            acc += a1v * sW1[1 * F1 + col];
            acc += a2  * sW1[2 * F1 + col];
            op[j] = fmaxf(acc, 0.0f);
        }
        hr[qq] = o;
    }
}

// ---------- layer 2: quad-gather + fused matmul + ReLU + segmented-scan pooling ----------
__global__ __launch_bounds__(256) void k_h2seg(const int* __restrict__ rowptr,
                                               const int* __restrict__ csr_src,
                                               const float* __restrict__ dis,
                                               const float* __restrict__ h1,
                                               const float* __restrict__ W2,
                                               const float* __restrict__ b2,
                                               const int* __restrict__ batch,
                                               float* __restrict__ gsum) {
    __shared__ float sW2[F1 * F2];
    __shared__ float sb2[F2];
    for (int i = threadIdx.x; i < F1 * F2; i += 256) sW2[i] = W2[i];
    if (threadIdx.x < F2) sb2[threadIdx.x] = b2[threadIdx.x];
    __syncthreads();
    int t = blockIdx.x * 256 + threadIdx.x;   // grid exact: t < 4*NN
    int n = t >> 2;                           // node
    int q = t & 3;                            // feature quad
    int lane = threadIdx.x & 63;
    int islot = lane >> 2;                    // node slot within wave (0..15)
    float dd = dis[n];
    int beg = rowptr[n], end = rowptr[n + 1];
    float ax = 0.f, ay = 0.f, az = 0.f, aw = 0.f;
    int e = beg;
    for (; e + 3 < end; e += 4) {
        int s0 = csr_src[e], s1 = csr_src[e+1], s2 = csr_src[e+2], s3 = csr_src[e+3];
        float m0 = dd * dis[s0], m1 = dd * dis[s1], m2 = dd * dis[s2], m3 = dd * dis[s3];
        float4 v0 = *(const float4*)(h1 + (size_t)s0 * F1 + q * 4);
        float4 v1 = *(const float4*)(h1 + (size_t)s1 * F1 + q * 4);
        float4 v2 = *(const float4*)(h1 + (size_t)s2 * F1 + q * 4);
        float4 v3 = *(const float4*)(h1 + (size_t)s3 * F1 + q * 4);
        ax += m0*v0.x + m1*v1.x + m2*v2.x + m3*v3.x;
        ay += m0*v0.y + m1*v1.y + m2*v2.y + m3*v3.y;
        az += m0*v0.z + m1*v1.z + m2*v2.z + m3*v3.z;
        aw += m0*v0.w + m1*v1.w + m2*v2.w + m3*v3.w;
    }
    for (; e < end; ++e) {
        int s_ = csr_src[e];
        float nrm = dd * dis[s_];
        float4 v = *(const float4*)(h1 + (size_t)s_ * F1 + q * 4);
        ax += nrm * v.x; ay += nrm * v.y; az += nrm * v.z; aw += nrm * v.w;
    }
    float sw = 2.0f * dd * dd;
    float4 hv4 = *(const float4*)(h1 + (size_t)n * F1 + q * 4);
    ax += sw * hv4.x; ay += sw * hv4.y; az += sw * hv4.z; aw += sw * hv4.w;

    // assemble full 16-vector in each lane of the quad
    int qbase = lane & ~3;
    float av[F1];
    #pragma unroll
    for (int k = 0; k < F1; ++k) {
        int kc = k & 3;
        float comp = (kc == 0) ? ax : (kc == 1) ? ay : (kc == 2) ? az : aw;
        av[k] = __shfl(comp, qbase + (k >> 2), 64);
    }

    // h2 slice: thread q computes output columns [8q, 8q+8)
    float hv[8];
    #pragma unroll
    for (int j0 = 0; j0 < 8; ++j0) {
        int j = q * 8 + j0;
        float acc = sb2[j];
        #pragma unroll
        for (int k = 0; k < F1; ++k) acc += av[k] * sW2[k * F2 + j];
        hv[j0] = fmaxf(acc, 0.0f);
    }

    // wave segmented inclusive scan over node slots (stride-4 lanes), seg = graph
    int g = batch[n];
    #pragma unroll
    for (int d_ = 1; d_ < 16; d_ <<= 1) {
        int sl = lane - 4 * d_;
        int gs = __shfl(g, sl, 64);
        #pragma unroll
        for (int j0 = 0; j0 < 8; ++j0) {
            float o = __shfl(hv[j0], sl, 64);
            if (islot >= d_ && gs == g) hv[j0] += o;
        }
    }
    int gn = __shfl(g, lane + 4, 64);
    bool endseg = (islot == 15) || (gn != g);
    if (endseg) {
        float* gr = gsum + (size_t)g * F2 + q * 8;
        #pragma unroll
        for (int j0 = 0; j0 < 8; ++j0) atomicAdd(gr + j0, hv[j0]);
    }
}

// ---------- head ----------
__global__ __launch_bounds__(256) void k_out2(const float* __restrict__ gsum,
                                              const int* __restrict__ gcnt,
                                              const float* __restrict__ Wl,
                                              const float* __restrict__ bl,
                                              float* __restrict__ out) {
    int t = blockIdx.x * 256 + threadIdx.x;
    if (t >= NG * NC) return;
    int g = t / NC, c = t - g * NC;
    float inv = 1.0f / fmaxf((float)gcnt[g], 1.0f);
    const float* gr = gsum + (size_t)g * F2;
    float acc = 0.0f;
    #pragma unroll
    for (int k = 0; k < F2; ++k) acc += gr[k] * Wl[k * NC + c];
    out[t] = acc * inv + bl[c];
}

// ---------------- launcher ----------------
extern "C" void kernel_launch(void* const* d_in, const int* in_sizes, int n_in,
                              void* d_out, int out_size, void* d_ws, size_t ws_size,
                              hipStream_t stream) {
    const float* x    = (const float*)d_in[0];
    const int*   ei   = (const int*)d_in[1];
    const int*   src  = ei;
    const int*   dst  = ei + NE;
    const int*   batch= (const int*)d_in[2];
    const float* W1   = (const float*)d_in[3];
    const float* b1   = (const float*)d_in[4];
    const float* W2   = (const float*)d_in[5];
    const float* b2   = (const float*)d_in[6];
    const float* Wl   = (const float*)d_in[7];
    const float* bl   = (const float*)d_in[8];
    float* out = (float*)d_out;

    // workspace layout (ebuf aliased with h1: ebuf dead after k_scatter2,
    // h1 written only afterwards by k_g1)
    int*   degI    = (int*)d_ws;                     // NN      (zeroed)
    int*   gcnt    = degI + NN;                      // NG      (zeroed)
    float* gsum    = (float*)(gcnt + NG);            // 32*NG   (zeroed)
    int*   rowptr  = (int*)(gsum + (size_t)F2 * NG); // NN+4
    int*   bsum    = rowptr + NN + 4;                // 256
    float* dis     = (float*)(bsum + 256);           // NN
    int*   gcur    = (int*)(dis + NN);               // NB
    int*   csr_src = gcur + NB;                      // NE
    int*   ebuf    = csr_src + NE;                   // NE (aliased)
    float* h1      = (float*)ebuf;                   // 16*NN (same bytes)

    size_t zero_elems = (size_t)NN + NG + (size_t)F2 * NG;
    hipMemsetAsync(d_ws, 0, zero_elems * sizeof(int), stream);

    k_deg     <<<NE / 4 / 256, 256, 0, stream>>>(dst, degI);
    k_dis     <<<NN / 256, 256, 0, stream>>>(degI, dis, batch, gcnt);
    k_scan1   <<<NN / 1024, 256, 0, stream>>>(degI, rowptr, bsum);
    k_scan2   <<<1, 256, 0, stream>>>(bsum, rowptr);
    k_scan3   <<<NN / 256, 256, 0, stream>>>(rowptr, bsum);
    k_bbase   <<<1, 256, 0, stream>>>(rowptr, gcur);
    k_bin     <<<NE / BINCH, 512, 0, stream>>>(src, dst, gcur, ebuf);
    k_scatter2<<<NB, 512, 0, stream>>>(rowptr, ebuf, csr_src);
    k_g1      <<<NN / 256, 256, 0, stream>>>(rowptr, csr_src, dis, x, W1, b1, h1);
    k_h2seg   <<<NN * 4 / 256, 256, 0, stream>>>(rowptr, csr_src, dis, h1, W2, b2, batch, gsum);
    k_out2    <<<(NG * NC + 255) / 256, 256, 0, stream>>>(gsum, gcnt, Wl, bl, out);
}

// Round 5
// 282.752 us; speedup vs baseline: 16.7573x; 1.5467x over previous
//
#include <hip/hip_runtime.h>

#define NN 262144   // nodes
#define NE 4194304  // edges (divisible by 16384)
#define NG 16384    // graphs
#define NC 26       // classes
#define F1 16
#define F2 32
#define NB 256      // dst buckets (1024 nodes each)
#define BINCH 16384 // edges per binning block

// ---------- bucket histogram: LDS hist -> 256 global atomics/block ----------
__global__ __launch_bounds__(512) void k_binhist(const int* __restrict__ dst,
                                                 int* __restrict__ bcnt) {
    __shared__ int hist[NB];
    int tid = threadIdx.x;
    if (tid < NB) hist[tid] = 0;
    __syncthreads();
    const int4* d4 = (const int4*)(dst + blockIdx.x * BINCH);
    #pragma unroll
    for (int k = 0; k < BINCH / 512 / 4; ++k) {   // 8 iters
        int4 d = d4[tid + k * 512];
        atomicAdd(&hist[d.x >> 10], 1);
        atomicAdd(&hist[d.y >> 10], 1);
        atomicAdd(&hist[d.z >> 10], 1);
        atomicAdd(&hist[d.w >> 10], 1);
    }
    __syncthreads();
    if (tid < NB) atomicAdd(&bcnt[tid], hist[tid]);
}

// ---------- scan bucket counts -> bbase[257]; init gcur ----------
__global__ __launch_bounds__(256) void k_bscan(const int* __restrict__ bcnt,
                                               int* __restrict__ bbase,
                                               int* __restrict__ gcur) {
    __shared__ int s[256];
    int tid = threadIdx.x;
    int v = bcnt[tid];
    s[tid] = v;
    __syncthreads();
    #pragma unroll
    for (int off = 1; off < 256; off <<= 1) {
        int val = (tid >= off) ? s[tid - off] : 0;
        __syncthreads();
        if (tid >= off) s[tid] += val;
        __syncthreads();
    }
    int excl = s[tid] - v;
    bbase[tid] = excl;
    gcur[tid] = excl;
    if (tid == 255) bbase[256] = NE;
}

// ---------- multisplit binning: ebuf bucket-contiguous, packed (src<<10|dl) ----------
__global__ __launch_bounds__(512) void k_bin(const int* __restrict__ src,
                                             const int* __restrict__ dst,
                                             int* __restrict__ gcur,
                                             int* __restrict__ ebuf) {
    __shared__ int hist[NB];
    __shared__ int base[NB];
    int tid = threadIdx.x;
    if (tid < NB) hist[tid] = 0;
    __syncthreads();
    int e0 = blockIdx.x * BINCH;
    const int4* d4 = (const int4*)(dst + e0);
    const int4* s4 = (const int4*)(src + e0);
    #pragma unroll
    for (int k = 0; k < BINCH / 512 / 4; ++k) {   // 8 iters
        int4 d = d4[tid + k * 512];
        atomicAdd(&hist[d.x >> 10], 1);
        atomicAdd(&hist[d.y >> 10], 1);
        atomicAdd(&hist[d.z >> 10], 1);
        atomicAdd(&hist[d.w >> 10], 1);
    }
    __syncthreads();
    if (tid < NB) {
        base[tid] = atomicAdd(&gcur[tid], hist[tid]);
        hist[tid] = 0;
    }
    __syncthreads();
    #pragma unroll
    for (int k = 0; k < BINCH / 512 / 4; ++k) {
        int4 d = d4[tid + k * 512];
        int4 s = s4[tid + k * 512];
        int b, pos;
        b = d.x >> 10; pos = base[b] + atomicAdd(&hist[b], 1); ebuf[pos] = (s.x << 10) | (d.x & 1023);
        b = d.y >> 10; pos = base[b] + atomicAdd(&hist[b], 1); ebuf[pos] = (s.y << 10) | (d.y & 1023);
        b = d.z >> 10; pos = base[b] + atomicAdd(&hist[b], 1); ebuf[pos] = (s.z << 10) | (d.z & 1023);
        b = d.w >> 10; pos = base[b] + atomicAdd(&hist[b], 1); ebuf[pos] = (s.w << 10) | (d.w & 1023);
    }
}

// ---------- per-bucket: LDS degree count + LDS scan -> rowptr/dis/gcnt + scatter ----------
__global__ __launch_bounds__(1024) void k_bucket(const int* __restrict__ bbase,
                                                 const int* __restrict__ ebuf,
                                                 const int* __restrict__ batch,
                                                 int* __restrict__ rowptr,
                                                 int* __restrict__ csr_src,
                                                 float* __restrict__ dis,
                                                 int* __restrict__ gcnt) {
    __shared__ int sdeg[1024];   // degree, then inclusive scan (in place)
    __shared__ int srow[1024];   // global CSR row start per local node
    __shared__ int scur[1024];   // scatter cursor per local node
    int tid = threadIdx.x;
    int b = blockIdx.x;
    int n0 = b << 10;
    sdeg[tid] = 0;
    __syncthreads();
    int beg = bbase[b], end = bbase[b + 1];
    for (int i = beg + tid; i < end; i += 1024)
        atomicAdd(&sdeg[((unsigned)ebuf[i]) & 1023u], 1);
    __syncthreads();
    int mydeg = sdeg[tid];
    // inclusive Hillis-Steele scan over 1024 elements
    #pragma unroll
    for (int off = 1; off < 1024; off <<= 1) {
        int val = (tid >= off) ? sdeg[tid - off] : 0;
        __syncthreads();
        if (tid >= off) sdeg[tid] += val;
        __syncthreads();
    }
    int row = beg + sdeg[tid] - mydeg;          // exclusive + bucket base
    srow[tid] = row;
    scur[tid] = 0;
    int n = n0 + tid;
    rowptr[n] = row;
    if (b == NB - 1 && tid == 1023) rowptr[NN] = NE;
    dis[n] = rsqrtf((float)mydeg + 2.0f);
    atomicAdd(&gcnt[batch[n]], 1);
    __syncthreads();
    for (int i = beg + tid; i < end; i += 1024) {
        unsigned p = (unsigned)ebuf[i];
        int dl = p & 1023u;
        int pos = srow[dl] + atomicAdd(&scur[dl], 1);
        csr_src[pos] = (int)(p >> 10);
    }
}

// ---------- layer 1: gather raw x + fused 3->16 matmul + ReLU (4x unroll) ----------
__global__ __launch_bounds__(256) void k_g1(const int* __restrict__ rowptr,
                                            const int* __restrict__ csr_src,
                                            const float* __restrict__ dis,
                                            const float* __restrict__ x,
                                            const float* __restrict__ W1,
                                            const float* __restrict__ b1,
                                            float* __restrict__ h1) {
    __shared__ float sW1[3 * F1];
    __shared__ float sb1[F1];
    if (threadIdx.x < 3 * F1) sW1[threadIdx.x] = W1[threadIdx.x];
    if (threadIdx.x < F1) sb1[threadIdx.x] = b1[threadIdx.x];
    __syncthreads();
    int n = blockIdx.x * 256 + threadIdx.x;
    float dd = dis[n];
    int beg = rowptr[n], end = rowptr[n + 1];
    float a0 = 0.f, a1v = 0.f, a2 = 0.f;
    int e = beg;
    for (; e + 3 < end; e += 4) {
        int s0 = csr_src[e], s1 = csr_src[e + 1], s2 = csr_src[e + 2], s3 = csr_src[e + 3];
        float m0 = dd * dis[s0], m1 = dd * dis[s1], m2 = dd * dis[s2], m3 = dd * dis[s3];
        float x00 = x[3*s0], x01 = x[3*s0+1], x02 = x[3*s0+2];
        float x10 = x[3*s1], x11 = x[3*s1+1], x12 = x[3*s1+2];
        float x20 = x[3*s2], x21 = x[3*s2+1], x22 = x[3*s2+2];
        float x30 = x[3*s3], x31 = x[3*s3+1], x32 = x[3*s3+2];
        a0  += m0*x00 + m1*x10 + m2*x20 + m3*x30;
        a1v += m0*x01 + m1*x11 + m2*x21 + m3*x31;
        a2  += m0*x02 + m1*x12 + m2*x22 + m3*x32;
    }
    for (; e < end; ++e) {
        int s_ = csr_src[e];
        float nrm = dd * dis[s_];
        a0  += nrm * x[3*s_ + 0];
        a1v += nrm * x[3*s_ + 1];
        a2  += nrm * x[3*s_ + 2];
    }
    float sw = 2.0f * dd * dd;
    a0  += sw * x[3*n + 0];
    a1v += sw * x[3*n + 1];
    a2  += sw * x[3*n + 2];
    float4* hr = (float4*)(h1 + (size_t)n * F1);
    #pragma unroll
    for (int qq = 0; qq < 4; ++qq) {
        float4 o;
        float* op = (float*)&o;
        #pragma unroll
        for (int j = 0; j < 4; ++j) {
            int col = qq * 4 + j;
            float acc = sb1[col];
            acc += a0  * sW1[0 * F1 + col];
            acc += a1v * sW1[1 * F1 + col];
            acc += a2  * sW1[2 * F1 + col];
            op[j] = fmaxf(acc, 0.0f);
        }
        hr[qq] = o;
    }
}

// ---------- layer 2: quad-gather + fused matmul + ReLU + segmented-scan pooling ----------
__global__ __launch_bounds__(256) void k_h2seg(const int* __restrict__ rowptr,
                                               const int* __restrict__ csr_src,
                                               const float* __restrict__ dis,
                                               const float* __restrict__ h1,
                                               const float* __restrict__ W2,
                                               const float* __restrict__ b2,
                                               const int* __restrict__ batch,
                                               float* __restrict__ gsum) {
    __shared__ float sW2[F1 * F2];
    __shared__ float sb2[F2];
    for (int i = threadIdx.x; i < F1 * F2; i += 256) sW2[i] = W2[i];
    if (threadIdx.x < F2) sb2[threadIdx.x] = b2[threadIdx.x];
    __syncthreads();
    int t = blockIdx.x * 256 + threadIdx.x;   // grid exact: t < 4*NN
    int n = t >> 2;                           // node
    int q = t & 3;                            // feature quad
    int lane = threadIdx.x & 63;
    int islot = lane >> 2;                    // node slot within wave (0..15)
    float dd = dis[n];
    int beg = rowptr[n], end = rowptr[n + 1];
    float ax = 0.f, ay = 0.f, az = 0.f, aw = 0.f;
    int e = beg;
    for (; e + 3 < end; e += 4) {
        int s0 = csr_src[e], s1 = csr_src[e+1], s2 = csr_src[e+2], s3 = csr_src[e+3];
        float m0 = dd * dis[s0], m1 = dd * dis[s1], m2 = dd * dis[s2], m3 = dd * dis[s3];
        float4 v0 = *(const float4*)(h1 + (size_t)s0 * F1 + q * 4);
        float4 v1 = *(const float4*)(h1 + (size_t)s1 * F1 + q * 4);
        float4 v2 = *(const float4*)(h1 + (size_t)s2 * F1 + q * 4);
        float4 v3 = *(const float4*)(h1 + (size_t)s3 * F1 + q * 4);
        ax += m0*v0.x + m1*v1.x + m2*v2.x + m3*v3.x;
        ay += m0*v0.y + m1*v1.y + m2*v2.y + m3*v3.y;
        az += m0*v0.z + m1*v1.z + m2*v2.z + m3*v3.z;
        aw += m0*v0.w + m1*v1.w + m2*v2.w + m3*v3.w;
    }
    for (; e < end; ++e) {
        int s_ = csr_src[e];
        float nrm = dd * dis[s_];
        float4 v = *(const float4*)(h1 + (size_t)s_ * F1 + q * 4);
        ax += nrm * v.x; ay += nrm * v.y; az += nrm * v.z; aw += nrm * v.w;
    }
    float sw = 2.0f * dd * dd;
    float4 hv4 = *(const float4*)(h1 + (size_t)n * F1 + q * 4);
    ax += sw * hv4.x; ay += sw * hv4.y; az += sw * hv4.z; aw += sw * hv4.w;

    // assemble full 16-vector in each lane of the quad
    int qbase = lane & ~3;
    float av[F1];
    #pragma unroll
    for (int k = 0; k < F1; ++k) {
        int kc = k & 3;
        float comp = (kc == 0) ? ax : (kc == 1) ? ay : (kc == 2) ? az : aw;
        av[k] = __shfl(comp, qbase + (k >> 2), 64);
    }

    // h2 slice: thread q computes output columns [8q, 8q+8)
    float hv[8];
    #pragma unroll
    for (int j0 = 0; j0 < 8; ++j0) {
        int j = q * 8 + j0;
        float acc = sb2[j];
        #pragma unroll
        for (int k = 0; k < F1; ++k) acc += av[k] * sW2[k * F2 + j];
        hv[j0] = fmaxf(acc, 0.0f);
    }

    // wave segmented inclusive scan over node slots (stride-4 lanes), seg = graph
    int g = batch[n];
    #pragma unroll
    for (int d_ = 1; d_ < 16; d_ <<= 1) {
        int sl = lane - 4 * d_;
        int gs = __shfl(g, sl, 64);
        #pragma unroll
        for (int j0 = 0; j0 < 8; ++j0) {
            float o = __shfl(hv[j0], sl, 64);
            if (islot >= d_ && gs == g) hv[j0] += o;
        }
    }
    int gn = __shfl(g, lane + 4, 64);
    bool endseg = (islot == 15) || (gn != g);
    if (endseg) {
        float* gr = gsum + (size_t)g * F2 + q * 8;
        #pragma unroll
        for (int j0 = 0; j0 < 8; ++j0) atomicAdd(gr + j0, hv[j0]);
    }
}

// ---------- head ----------
__global__ __launch_bounds__(256) void k_out2(const float* __restrict__ gsum,
                                              const int* __restrict__ gcnt,
                                              const float* __restrict__ Wl,
                                              const float* __restrict__ bl,
                                              float* __restrict__ out) {
    int t = blockIdx.x * 256 + threadIdx.x;
    if (t >= NG * NC) return;
    int g = t / NC, c = t - g * NC;
    float inv = 1.0f / fmaxf((float)gcnt[g], 1.0f);
    const float* gr = gsum + (size_t)g * F2;
    float acc = 0.0f;
    #pragma unroll
    for (int k = 0; k < F2; ++k) acc += gr[k] * Wl[k * NC + c];
    out[t] = acc * inv + bl[c];
}

// ---------------- launcher ----------------
extern "C" void kernel_launch(void* const* d_in, const int* in_sizes, int n_in,
                              void* d_out, int out_size, void* d_ws, size_t ws_size,
                              hipStream_t stream) {
    const float* x    = (const float*)d_in[0];
    const int*   ei   = (const int*)d_in[1];
    const int*   src  = ei;
    const int*   dst  = ei + NE;
    const int*   batch= (const int*)d_in[2];
    const float* W1   = (const float*)d_in[3];
    const float* b1   = (const float*)d_in[4];
    const float* W2   = (const float*)d_in[5];
    const float* b2   = (const float*)d_in[6];
    const float* Wl   = (const float*)d_in[7];
    const float* bl   = (const float*)d_in[8];
    float* out = (float*)d_out;

    // workspace layout — zeroed region first: bcnt, gcnt, gsum
    int*   bcnt    = (int*)d_ws;                     // NB      (zeroed)
    int*   gcnt    = bcnt + NB;                      // NG      (zeroed)
    float* gsum    = (float*)(gcnt + NG);            // 32*NG   (zeroed)
    int*   bbase   = (int*)(gsum + (size_t)F2 * NG); // 257 (+pad 3)
    int*   gcur    = bbase + 260;                    // NB
    int*   rowptr  = gcur + NB;                      // NN+4
    float* dis     = (float*)(rowptr + NN + 4);      // NN
    int*   csr_src = (int*)(dis + NN);               // NE
    int*   ebuf    = csr_src + NE;                   // NE (aliased with h1)
    float* h1      = (float*)ebuf;                   // 16*NN (same bytes; ebuf dead by k_g1)

    size_t zero_elems = (size_t)NB + NG + (size_t)F2 * NG;
    hipMemsetAsync(d_ws, 0, zero_elems * sizeof(int), stream);

    k_binhist<<<NE / BINCH, 512, 0, stream>>>(dst, bcnt);
    k_bscan  <<<1, 256, 0, stream>>>(bcnt, bbase, gcur);
    k_bin    <<<NE / BINCH, 512, 0, stream>>>(src, dst, gcur, ebuf);
    k_bucket <<<NB, 1024, 0, stream>>>(bbase, ebuf, batch, rowptr, csr_src, dis, gcnt);
    k_g1     <<<NN / 256, 256, 0, stream>>>(rowptr, csr_src, dis, x, W1, b1, h1);
    k_h2seg  <<<NN * 4 / 256, 256, 0, stream>>>(rowptr, csr_src, dis, h1, W2, b2, batch, gsum);
    k_out2   <<<(NG * NC + 255) / 256, 256, 0, stream>>>(gsum, gcnt, Wl, bl, out);
}

// Round 6
// 239.319 us; speedup vs baseline: 19.7986x; 1.1815x over previous
//
#include <hip/hip_runtime.h>
#include <hip/hip_fp16.h>

#define NN 262144   // nodes
#define NE 4194304  // edges (divisible by 16384)
#define NG 16384    // graphs
#define NC 26       // classes
#define F1 16
#define F2 32
#define NB 256      // dst buckets (1024 nodes each)
#define BINCH 16384 // edges per binning block

// ---------- bucket histogram: LDS hist -> 256 global atomics/block ----------
__global__ __launch_bounds__(512) void k_binhist(const int* __restrict__ dst,
                                                 int* __restrict__ bcnt) {
    __shared__ int hist[NB];
    int tid = threadIdx.x;
    if (tid < NB) hist[tid] = 0;
    __syncthreads();
    const int4* d4 = (const int4*)(dst + blockIdx.x * BINCH);
    #pragma unroll
    for (int k = 0; k < BINCH / 512 / 4; ++k) {   // 8 iters
        int4 d = d4[tid + k * 512];
        atomicAdd(&hist[d.x >> 10], 1);
        atomicAdd(&hist[d.y >> 10], 1);
        atomicAdd(&hist[d.z >> 10], 1);
        atomicAdd(&hist[d.w >> 10], 1);
    }
    __syncthreads();
    if (tid < NB) atomicAdd(&bcnt[tid], hist[tid]);
}

// ---------- scan bucket counts -> bbase[257]; init gcur ----------
__global__ __launch_bounds__(256) void k_bscan(const int* __restrict__ bcnt,
                                               int* __restrict__ bbase,
                                               int* __restrict__ gcur) {
    __shared__ int s[256];
    int tid = threadIdx.x;
    int v = bcnt[tid];
    s[tid] = v;
    __syncthreads();
    #pragma unroll
    for (int off = 1; off < 256; off <<= 1) {
        int val = (tid >= off) ? s[tid - off] : 0;
        __syncthreads();
        if (tid >= off) s[tid] += val;
        __syncthreads();
    }
    int excl = s[tid] - v;
    bbase[tid] = excl;
    gcur[tid] = excl;
    if (tid == 255) bbase[256] = NE;
}

// ---------- multisplit binning: ebuf bucket-contiguous, packed (src<<10|dl) ----------
__global__ __launch_bounds__(512) void k_bin(const int* __restrict__ src,
                                             const int* __restrict__ dst,
                                             int* __restrict__ gcur,
                                             int* __restrict__ ebuf) {
    __shared__ int hist[NB];
    __shared__ int base[NB];
    int tid = threadIdx.x;
    if (tid < NB) hist[tid] = 0;
    __syncthreads();
    int e0 = blockIdx.x * BINCH;
    const int4* d4 = (const int4*)(dst + e0);
    const int4* s4 = (const int4*)(src + e0);
    #pragma unroll
    for (int k = 0; k < BINCH / 512 / 4; ++k) {   // 8 iters
        int4 d = d4[tid + k * 512];
        atomicAdd(&hist[d.x >> 10], 1);
        atomicAdd(&hist[d.y >> 10], 1);
        atomicAdd(&hist[d.z >> 10], 1);
        atomicAdd(&hist[d.w >> 10], 1);
    }
    __syncthreads();
    if (tid < NB) {
        base[tid] = atomicAdd(&gcur[tid], hist[tid]);
        hist[tid] = 0;
    }
    __syncthreads();
    #pragma unroll
    for (int k = 0; k < BINCH / 512 / 4; ++k) {
        int4 d = d4[tid + k * 512];
        int4 s = s4[tid + k * 512];
        int b, pos;
        b = d.x >> 10; pos = base[b] + atomicAdd(&hist[b], 1); ebuf[pos] = (s.x << 10) | (d.x & 1023);
        b = d.y >> 10; pos = base[b] + atomicAdd(&hist[b], 1); ebuf[pos] = (s.y << 10) | (d.y & 1023);
        b = d.z >> 10; pos = base[b] + atomicAdd(&hist[b], 1); ebuf[pos] = (s.z << 10) | (d.z & 1023);
        b = d.w >> 10; pos = base[b] + atomicAdd(&hist[b], 1); ebuf[pos] = (s.w << 10) | (d.w & 1023);
    }
}

// ---------- per-bucket: LDS degree count + LDS scan -> rowptr/dis/gcnt + scatter ----------
__global__ __launch_bounds__(1024) void k_bucket(const int* __restrict__ bbase,
                                                 const int* __restrict__ ebuf,
                                                 const int* __restrict__ batch,
                                                 int* __restrict__ rowptr,
                                                 int* __restrict__ csr_src,
                                                 float* __restrict__ dis,
                                                 int* __restrict__ gcnt) {
    __shared__ int sdeg[1024];   // degree, then inclusive scan (in place)
    __shared__ int srow[1024];   // global CSR row start per local node
    __shared__ int scur[1024];   // scatter cursor per local node
    int tid = threadIdx.x;
    int b = blockIdx.x;
    int n0 = b << 10;
    sdeg[tid] = 0;
    __syncthreads();
    int beg = bbase[b], end = bbase[b + 1];
    for (int i = beg + tid; i < end; i += 1024)
        atomicAdd(&sdeg[((unsigned)ebuf[i]) & 1023u], 1);
    __syncthreads();
    int mydeg = sdeg[tid];
    // inclusive Hillis-Steele scan over 1024 elements
    #pragma unroll
    for (int off = 1; off < 1024; off <<= 1) {
        int val = (tid >= off) ? sdeg[tid - off] : 0;
        __syncthreads();
        if (tid >= off) sdeg[tid] += val;
        __syncthreads();
    }
    int row = beg + sdeg[tid] - mydeg;          // exclusive + bucket base
    srow[tid] = row;
    scur[tid] = 0;
    int n = n0 + tid;
    rowptr[n] = row;
    if (b == NB - 1 && tid == 1023) rowptr[NN] = NE;
    dis[n] = rsqrtf((float)mydeg + 2.0f);
    atomicAdd(&gcnt[batch[n]], 1);
    __syncthreads();
    for (int i = beg + tid; i < end; i += 1024) {
        unsigned p = (unsigned)ebuf[i];
        int dl = p & 1023u;
        int pos = srow[dl] + atomicAdd(&scur[dl], 1);
        csr_src[pos] = (int)(p >> 10);
    }
}

// ---------- layer 1: gather raw x + fused 3->16 matmul + ReLU -> fp16 h1 ----------
__global__ __launch_bounds__(256) void k_g1(const int* __restrict__ rowptr,
                                            const int* __restrict__ csr_src,
                                            const float* __restrict__ dis,
                                            const float* __restrict__ x,
                                            const float* __restrict__ W1,
                                            const float* __restrict__ b1,
                                            __half* __restrict__ h1) {
    __shared__ float sW1[3 * F1];
    __shared__ float sb1[F1];
    if (threadIdx.x < 3 * F1) sW1[threadIdx.x] = W1[threadIdx.x];
    if (threadIdx.x < F1) sb1[threadIdx.x] = b1[threadIdx.x];
    __syncthreads();
    int n = blockIdx.x * 256 + threadIdx.x;
    float dd = dis[n];
    int beg = rowptr[n], end = rowptr[n + 1];
    float a0 = 0.f, a1v = 0.f, a2 = 0.f;
    int e = beg;
    for (; e + 3 < end; e += 4) {
        int s0 = csr_src[e], s1 = csr_src[e + 1], s2 = csr_src[e + 2], s3 = csr_src[e + 3];
        float m0 = dd * dis[s0], m1 = dd * dis[s1], m2 = dd * dis[s2], m3 = dd * dis[s3];
        float x00 = x[3*s0], x01 = x[3*s0+1], x02 = x[3*s0+2];
        float x10 = x[3*s1], x11 = x[3*s1+1], x12 = x[3*s1+2];
        float x20 = x[3*s2], x21 = x[3*s2+1], x22 = x[3*s2+2];
        float x30 = x[3*s3], x31 = x[3*s3+1], x32 = x[3*s3+2];
        a0  += m0*x00 + m1*x10 + m2*x20 + m3*x30;
        a1v += m0*x01 + m1*x11 + m2*x21 + m3*x31;
        a2  += m0*x02 + m1*x12 + m2*x22 + m3*x32;
    }
    for (; e < end; ++e) {
        int s_ = csr_src[e];
        float nrm = dd * dis[s_];
        a0  += nrm * x[3*s_ + 0];
        a1v += nrm * x[3*s_ + 1];
        a2  += nrm * x[3*s_ + 2];
    }
    float sw = 2.0f * dd * dd;
    a0  += sw * x[3*n + 0];
    a1v += sw * x[3*n + 1];
    a2  += sw * x[3*n + 2];
    float vals[F1];
    #pragma unroll
    for (int col = 0; col < F1; ++col) {
        float acc = sb1[col];
        acc += a0  * sW1[0 * F1 + col];
        acc += a1v * sW1[1 * F1 + col];
        acc += a2  * sW1[2 * F1 + col];
        vals[col] = fmaxf(acc, 0.0f);
    }
    unsigned u[8];
    #pragma unroll
    for (int p = 0; p < 8; ++p) {
        __half2 hp = __floats2half2_rn(vals[2 * p], vals[2 * p + 1]);
        u[p] = *(unsigned*)&hp;
    }
    uint4* hr = (uint4*)(h1 + ((size_t)n << 4));   // 32B row = 2x uint4
    hr[0] = make_uint4(u[0], u[1], u[2], u[3]);
    hr[1] = make_uint4(u[4], u[5], u[6], u[7]);
}

// ---------- layer 2: quad-gather fp16 h1 + fused matmul + ReLU + segmented-scan pooling ----------
__global__ __launch_bounds__(256) void k_h2seg(const int* __restrict__ rowptr,
                                               const int* __restrict__ csr_src,
                                               const float* __restrict__ dis,
                                               const __half* __restrict__ h1,
                                               const float* __restrict__ W2,
                                               const float* __restrict__ b2,
                                               const int* __restrict__ batch,
                                               float* __restrict__ gsum) {
    __shared__ float sW2[F1 * F2];
    __shared__ float sb2[F2];
    for (int i = threadIdx.x; i < F1 * F2; i += 256) sW2[i] = W2[i];
    if (threadIdx.x < F2) sb2[threadIdx.x] = b2[threadIdx.x];
    __syncthreads();
    int t = blockIdx.x * 256 + threadIdx.x;   // grid exact: t < 4*NN
    int n = t >> 2;                           // node
    int q = t & 3;                            // feature quad (4 halves = 8B)
    int lane = threadIdx.x & 63;
    int islot = lane >> 2;                    // node slot within wave (0..15)
    float dd = dis[n];
    int beg = rowptr[n], end = rowptr[n + 1];
    float ax = 0.f, ay = 0.f, az = 0.f, aw = 0.f;
    int e = beg;
    int qoff = q << 2;
    for (; e + 3 < end; e += 4) {
        int s0 = csr_src[e], s1 = csr_src[e+1], s2 = csr_src[e+2], s3 = csr_src[e+3];
        float m0 = dd * dis[s0], m1 = dd * dis[s1], m2 = dd * dis[s2], m3 = dd * dis[s3];
        uint2 r0 = *(const uint2*)(h1 + ((size_t)s0 << 4) + qoff);
        uint2 r1 = *(const uint2*)(h1 + ((size_t)s1 << 4) + qoff);
        uint2 r2 = *(const uint2*)(h1 + ((size_t)s2 << 4) + qoff);
        uint2 r3 = *(const uint2*)(h1 + ((size_t)s3 << 4) + qoff);
        float2 a0_ = __half22float2(*(__half2*)&r0.x), b0_ = __half22float2(*(__half2*)&r0.y);
        float2 a1_ = __half22float2(*(__half2*)&r1.x), b1_ = __half22float2(*(__half2*)&r1.y);
        float2 a2_ = __half22float2(*(__half2*)&r2.x), b2_ = __half22float2(*(__half2*)&r2.y);
        float2 a3_ = __half22float2(*(__half2*)&r3.x), b3_ = __half22float2(*(__half2*)&r3.y);
        ax += m0*a0_.x + m1*a1_.x + m2*a2_.x + m3*a3_.x;
        ay += m0*a0_.y + m1*a1_.y + m2*a2_.y + m3*a3_.y;
        az += m0*b0_.x + m1*b1_.x + m2*b2_.x + m3*b3_.x;
        aw += m0*b0_.y + m1*b1_.y + m2*b2_.y + m3*b3_.y;
    }
    for (; e < end; ++e) {
        int s_ = csr_src[e];
        float nrm = dd * dis[s_];
        uint2 r = *(const uint2*)(h1 + ((size_t)s_ << 4) + qoff);
        float2 fa = __half22float2(*(__half2*)&r.x), fb = __half22float2(*(__half2*)&r.y);
        ax += nrm * fa.x; ay += nrm * fa.y; az += nrm * fb.x; aw += nrm * fb.y;
    }
    float sw = 2.0f * dd * dd;
    {
        uint2 r = *(const uint2*)(h1 + ((size_t)n << 4) + qoff);
        float2 fa = __half22float2(*(__half2*)&r.x), fb = __half22float2(*(__half2*)&r.y);
        ax += sw * fa.x; ay += sw * fa.y; az += sw * fb.x; aw += sw * fb.y;
    }

    // assemble full 16-vector in each lane of the quad
    int qbase = lane & ~3;
    float av[F1];
    #pragma unroll
    for (int k = 0; k < F1; ++k) {
        int kc = k & 3;
        float comp = (kc == 0) ? ax : (kc == 1) ? ay : (kc == 2) ? az : aw;
        av[k] = __shfl(comp, qbase + (k >> 2), 64);
    }

    // h2 slice: thread q computes output columns [8q, 8q+8)
    float hv[8];
    #pragma unroll
    for (int j0 = 0; j0 < 8; ++j0) {
        int j = q * 8 + j0;
        float acc = sb2[j];
        #pragma unroll
        for (int k = 0; k < F1; ++k) acc += av[k] * sW2[k * F2 + j];
        hv[j0] = fmaxf(acc, 0.0f);
    }

    // wave segmented inclusive scan over node slots (stride-4 lanes), seg = graph
    int g = batch[n];
    #pragma unroll
    for (int d_ = 1; d_ < 16; d_ <<= 1) {
        int sl = lane - 4 * d_;
        int gs = __shfl(g, sl, 64);
        #pragma unroll
        for (int j0 = 0; j0 < 8; ++j0) {
            float o = __shfl(hv[j0], sl, 64);
            if (islot >= d_ && gs == g) hv[j0] += o;
        }
    }
    int gn = __shfl(g, lane + 4, 64);
    bool endseg = (islot == 15) || (gn != g);
    if (endseg) {
        float* gr = gsum + (size_t)g * F2 + q * 8;
        #pragma unroll
        for (int j0 = 0; j0 < 8; ++j0) atomicAdd(gr + j0, hv[j0]);
    }
}

// ---------- head ----------
__global__ __launch_bounds__(256) void k_out2(const float* __restrict__ gsum,
                                              const int* __restrict__ gcnt,
                                              const float* __restrict__ Wl,
                                              const float* __restrict__ bl,
                                              float* __restrict__ out) {
    int t = blockIdx.x * 256 + threadIdx.x;
    if (t >= NG * NC) return;
    int g = t / NC, c = t - g * NC;
    float inv = 1.0f / fmaxf((float)gcnt[g], 1.0f);
    const float* gr = gsum + (size_t)g * F2;
    float acc = 0.0f;
    #pragma unroll
    for (int k = 0; k < F2; ++k) acc += gr[k] * Wl[k * NC + c];
    out[t] = acc * inv + bl[c];
}

// ---------------- launcher ----------------
extern "C" void kernel_launch(void* const* d_in, const int* in_sizes, int n_in,
                              void* d_out, int out_size, void* d_ws, size_t ws_size,
                              hipStream_t stream) {
    const float* x    = (const float*)d_in[0];
    const int*   ei   = (const int*)d_in[1];
    const int*   src  = ei;
    const int*   dst  = ei + NE;
    const int*   batch= (const int*)d_in[2];
    const float* W1   = (const float*)d_in[3];
    const float* b1   = (const float*)d_in[4];
    const float* W2   = (const float*)d_in[5];
    const float* b2   = (const float*)d_in[6];
    const float* Wl   = (const float*)d_in[7];
    const float* bl   = (const float*)d_in[8];
    float* out = (float*)d_out;

    // workspace layout — zeroed region first: bcnt, gcnt, gsum
    int*   bcnt    = (int*)d_ws;                     // NB      (zeroed)
    int*   gcnt    = bcnt + NB;                      // NG      (zeroed)
    float* gsum    = (float*)(gcnt + NG);            // 32*NG   (zeroed)
    int*   bbase   = (int*)(gsum + (size_t)F2 * NG); // 257 (+pad 3)
    int*   gcur    = bbase + 260;                    // NB
    int*   rowptr  = gcur + NB;                      // NN+4
    float* dis     = (float*)(rowptr + NN + 4);      // NN
    int*   csr_src = (int*)(dis + NN);               // NE
    int*   ebuf    = csr_src + NE;                   // NE (aliased with h1)
    __half* h1     = (__half*)ebuf;                  // 16*NN halves = 8MB (ebuf dead by k_g1)

    size_t zero_elems = (size_t)NB + NG + (size_t)F2 * NG;
    hipMemsetAsync(d_ws, 0, zero_elems * sizeof(int), stream);

    k_binhist<<<NE / BINCH, 512, 0, stream>>>(dst, bcnt);
    k_bscan  <<<1, 256, 0, stream>>>(bcnt, bbase, gcur);
    k_bin    <<<NE / BINCH, 512, 0, stream>>>(src, dst, gcur, ebuf);
    k_bucket <<<NB, 1024, 0, stream>>>(bbase, ebuf, batch, rowptr, csr_src, dis, gcnt);
    k_g1     <<<NN / 256, 256, 0, stream>>>(rowptr, csr_src, dis, x, W1, b1, h1);
    k_h2seg  <<<NN * 4 / 256, 256, 0, stream>>>(rowptr, csr_src, dis, h1, W2, b2, batch, gsum);
    k_out2   <<<(NG * NC + 255) / 256, 256, 0, stream>>>(gsum, gcnt, Wl, bl, out);
}

// Round 7
// 221.436 us; speedup vs baseline: 21.3975x; 1.0808x over previous
//
#include <hip/hip_runtime.h>
#include <hip/hip_fp16.h>

#define NN 262144   // nodes
#define NE 4194304  // edges (divisible by 16384)
#define NG 16384    // graphs
#define NC 26       // classes
#define F1 16
#define F2 32
#define NB 256      // dst buckets (1024 nodes each)
#define BINCH 16384 // edges per binning block

// ---------- bucket histogram: LDS hist -> 256 global atomics/block ----------
__global__ __launch_bounds__(512) void k_binhist(const int* __restrict__ dst,
                                                 int* __restrict__ bcnt) {
    __shared__ int hist[NB];
    int tid = threadIdx.x;
    if (tid < NB) hist[tid] = 0;
    __syncthreads();
    const int4* d4 = (const int4*)(dst + blockIdx.x * BINCH);
    #pragma unroll
    for (int k = 0; k < BINCH / 512 / 4; ++k) {   // 8 iters
        int4 d = d4[tid + k * 512];
        atomicAdd(&hist[d.x >> 10], 1);
        atomicAdd(&hist[d.y >> 10], 1);
        atomicAdd(&hist[d.z >> 10], 1);
        atomicAdd(&hist[d.w >> 10], 1);
    }
    __syncthreads();
    if (tid < NB) atomicAdd(&bcnt[tid], hist[tid]);
}

// ---------- scan bucket counts -> bbase[257]; init gcur ----------
__global__ __launch_bounds__(256) void k_bscan(const int* __restrict__ bcnt,
                                               int* __restrict__ bbase,
                                               int* __restrict__ gcur) {
    __shared__ int s[256];
    int tid = threadIdx.x;
    int v = bcnt[tid];
    s[tid] = v;
    __syncthreads();
    #pragma unroll
    for (int off = 1; off < 256; off <<= 1) {
        int val = (tid >= off) ? s[tid - off] : 0;
        __syncthreads();
        if (tid >= off) s[tid] += val;
        __syncthreads();
    }
    int excl = s[tid] - v;
    bbase[tid] = excl;
    gcur[tid] = excl;
    if (tid == 255) bbase[256] = NE;
}

// ---------- multisplit binning: ebuf bucket-contiguous, packed (src<<10|dl) ----------
__global__ __launch_bounds__(512) void k_bin(const int* __restrict__ src,
                                             const int* __restrict__ dst,
                                             int* __restrict__ gcur,
                                             int* __restrict__ ebuf) {
    __shared__ int hist[NB];
    __shared__ int base[NB];
    int tid = threadIdx.x;
    if (tid < NB) hist[tid] = 0;
    __syncthreads();
    int e0 = blockIdx.x * BINCH;
    const int4* d4 = (const int4*)(dst + e0);
    const int4* s4 = (const int4*)(src + e0);
    #pragma unroll
    for (int k = 0; k < BINCH / 512 / 4; ++k) {   // 8 iters
        int4 d = d4[tid + k * 512];
        atomicAdd(&hist[d.x >> 10], 1);
        atomicAdd(&hist[d.y >> 10], 1);
        atomicAdd(&hist[d.z >> 10], 1);
        atomicAdd(&hist[d.w >> 10], 1);
    }
    __syncthreads();
    if (tid < NB) {
        base[tid] = atomicAdd(&gcur[tid], hist[tid]);
        hist[tid] = 0;
    }
    __syncthreads();
    #pragma unroll
    for (int k = 0; k < BINCH / 512 / 4; ++k) {
        int4 d = d4[tid + k * 512];
        int4 s = s4[tid + k * 512];
        int b, pos;
        b = d.x >> 10; pos = base[b] + atomicAdd(&hist[b], 1); ebuf[pos] = (s.x << 10) | (d.x & 1023);
        b = d.y >> 10; pos = base[b] + atomicAdd(&hist[b], 1); ebuf[pos] = (s.y << 10) | (d.y & 1023);
        b = d.z >> 10; pos = base[b] + atomicAdd(&hist[b], 1); ebuf[pos] = (s.z << 10) | (d.z & 1023);
        b = d.w >> 10; pos = base[b] + atomicAdd(&hist[b], 1); ebuf[pos] = (s.w << 10) | (d.w & 1023);
    }
}

// ---------- per-bucket: LDS degree count + scan -> rowptr/dis/xs/gcnt + scatter ----------
__global__ __launch_bounds__(1024) void k_bucket(const int* __restrict__ bbase,
                                                 const int* __restrict__ ebuf,
                                                 const int* __restrict__ batch,
                                                 const float* __restrict__ x,
                                                 int* __restrict__ rowptr,
                                                 int* __restrict__ csr_src,
                                                 float* __restrict__ dis,
                                                 uint2* __restrict__ xs,
                                                 int* __restrict__ gcnt) {
    __shared__ int sdeg[1024];   // degree, then inclusive scan (in place)
    __shared__ int srow[1024];   // global CSR row start per local node
    __shared__ int scur[1024];   // scatter cursor per local node
    int tid = threadIdx.x;
    int b = blockIdx.x;
    int n0 = b << 10;
    sdeg[tid] = 0;
    __syncthreads();
    int beg = bbase[b], end = bbase[b + 1];
    for (int i = beg + tid; i < end; i += 1024)
        atomicAdd(&sdeg[((unsigned)ebuf[i]) & 1023u], 1);
    __syncthreads();
    int mydeg = sdeg[tid];
    // inclusive Hillis-Steele scan over 1024 elements
    #pragma unroll
    for (int off = 1; off < 1024; off <<= 1) {
        int val = (tid >= off) ? sdeg[tid - off] : 0;
        __syncthreads();
        if (tid >= off) sdeg[tid] += val;
        __syncthreads();
    }
    int row = beg + sdeg[tid] - mydeg;          // exclusive + bucket base
    srow[tid] = row;
    scur[tid] = 0;
    int n = n0 + tid;
    rowptr[n] = row;
    if (b == NB - 1 && tid == 1023) rowptr[NN] = NE;
    float ddn = rsqrtf((float)mydeg + 2.0f);
    dis[n] = ddn;
    // prescaled features xs = dis[n]*x[n], packed half4 (8B)
    float xv0 = x[3 * n], xv1 = x[3 * n + 1], xv2 = x[3 * n + 2];
    __half2 p0 = __floats2half2_rn(ddn * xv0, ddn * xv1);
    __half2 p1 = __floats2half2_rn(ddn * xv2, 0.0f);
    xs[n] = make_uint2(*(unsigned*)&p0, *(unsigned*)&p1);
    atomicAdd(&gcnt[batch[n]], 1);
    __syncthreads();
    for (int i = beg + tid; i < end; i += 1024) {
        unsigned p = (unsigned)ebuf[i];
        int dl = p & 1023u;
        int pos = srow[dl] + atomicAdd(&scur[dl], 1);
        csr_src[pos] = (int)(p >> 10);
    }
}

// ---------- layer 1: gather xs (pure sum) + 3->16 matmul + ReLU -> h1s = dis*h1 (fp16) ----------
__global__ __launch_bounds__(256) void k_g1(const int* __restrict__ rowptr,
                                            const int* __restrict__ csr_src,
                                            const float* __restrict__ dis,
                                            const uint2* __restrict__ xs,
                                            const float* __restrict__ W1,
                                            const float* __restrict__ b1,
                                            __half* __restrict__ h1s) {
    __shared__ float sW1[3 * F1];
    __shared__ float sb1[F1];
    if (threadIdx.x < 3 * F1) sW1[threadIdx.x] = W1[threadIdx.x];
    if (threadIdx.x < F1) sb1[threadIdx.x] = b1[threadIdx.x];
    __syncthreads();
    int n = blockIdx.x * 256 + threadIdx.x;
    float dd = dis[n];
    int beg = rowptr[n], end = rowptr[n + 1];
    float a0 = 0.f, a1v = 0.f, a2 = 0.f;
    int e = beg;
    for (; e + 3 < end; e += 4) {
        int s0 = csr_src[e], s1 = csr_src[e + 1], s2 = csr_src[e + 2], s3 = csr_src[e + 3];
        uint2 r0 = xs[s0], r1 = xs[s1], r2 = xs[s2], r3 = xs[s3];
        float2 l0 = __half22float2(*(__half2*)&r0.x), h0 = __half22float2(*(__half2*)&r0.y);
        float2 l1 = __half22float2(*(__half2*)&r1.x), h1_ = __half22float2(*(__half2*)&r1.y);
        float2 l2 = __half22float2(*(__half2*)&r2.x), h2_ = __half22float2(*(__half2*)&r2.y);
        float2 l3 = __half22float2(*(__half2*)&r3.x), h3_ = __half22float2(*(__half2*)&r3.y);
        a0  += l0.x + l1.x + l2.x + l3.x;
        a1v += l0.y + l1.y + l2.y + l3.y;
        a2  += h0.x + h1_.x + h2_.x + h3_.x;
    }
    for (; e < end; ++e) {
        int s_ = csr_src[e];
        uint2 r = xs[s_];
        float2 lo = __half22float2(*(__half2*)&r.x), hi = __half22float2(*(__half2*)&r.y);
        a0 += lo.x; a1v += lo.y; a2 += hi.x;
    }
    // self term: + 2*xs[n]; whole aggregate scaled by dd
    {
        uint2 rn = xs[n];
        float2 lo = __half22float2(*(__half2*)&rn.x), hi = __half22float2(*(__half2*)&rn.y);
        a0 += 2.0f * lo.x; a1v += 2.0f * lo.y; a2 += 2.0f * hi.x;
    }
    float g0 = dd * a0, g1 = dd * a1v, g2 = dd * a2;
    float vals[F1];
    #pragma unroll
    for (int col = 0; col < F1; ++col) {
        float acc = sb1[col];
        acc += g0 * sW1[0 * F1 + col];
        acc += g1 * sW1[1 * F1 + col];
        acc += g2 * sW1[2 * F1 + col];
        vals[col] = dd * fmaxf(acc, 0.0f);    // h1s = dis[n] * relu(...)
    }
    unsigned u[8];
    #pragma unroll
    for (int p = 0; p < 8; ++p) {
        __half2 hp = __floats2half2_rn(vals[2 * p], vals[2 * p + 1]);
        u[p] = *(unsigned*)&hp;
    }
    uint4* hr = (uint4*)(h1s + ((size_t)n << 4));
    hr[0] = make_uint4(u[0], u[1], u[2], u[3]);
    hr[1] = make_uint4(u[4], u[5], u[6], u[7]);
}

// ---------- layer 2: 2 threads/node, 16B gathers (pure sum) + matmul + ReLU + seg-scan pool ----------
__global__ __launch_bounds__(256) void k_h2seg(const int* __restrict__ rowptr,
                                               const int* __restrict__ csr_src,
                                               const float* __restrict__ dis,
                                               const __half* __restrict__ h1s,
                                               const float* __restrict__ W2,
                                               const float* __restrict__ b2,
                                               const int* __restrict__ batch,
                                               float* __restrict__ gsum) {
    __shared__ float sW2[F1 * F2];
    __shared__ float sb2[F2];
    for (int i = threadIdx.x; i < F1 * F2; i += 256) sW2[i] = W2[i];
    if (threadIdx.x < F2) sb2[threadIdx.x] = b2[threadIdx.x];
    __syncthreads();
    int t = blockIdx.x * 256 + threadIdx.x;   // grid exact: t < 2*NN
    int n = t >> 1;                           // node
    int h = t & 1;                            // row half (8 halves = 16B)
    int lane = threadIdx.x & 63;
    int islot = lane >> 1;                    // node slot within wave (0..31)
    float dd = dis[n];
    int beg = rowptr[n], end = rowptr[n + 1];
    float ac0 = 0.f, ac1 = 0.f, ac2 = 0.f, ac3 = 0.f,
          ac4 = 0.f, ac5 = 0.f, ac6 = 0.f, ac7 = 0.f;
    size_t off = (size_t)(h << 3);
    int e = beg;
    for (; e + 3 < end; e += 4) {
        int s0 = csr_src[e], s1 = csr_src[e+1], s2 = csr_src[e+2], s3 = csr_src[e+3];
        uint4 r0 = *(const uint4*)(h1s + (((size_t)s0 << 4) + off));
        uint4 r1 = *(const uint4*)(h1s + (((size_t)s1 << 4) + off));
        uint4 r2 = *(const uint4*)(h1s + (((size_t)s2 << 4) + off));
        uint4 r3 = *(const uint4*)(h1s + (((size_t)s3 << 4) + off));
        float2 f;
        f = __half22float2(*(__half2*)&r0.x); ac0 += f.x; ac1 += f.y;
        f = __half22float2(*(__half2*)&r0.y); ac2 += f.x; ac3 += f.y;
        f = __half22float2(*(__half2*)&r0.z); ac4 += f.x; ac5 += f.y;
        f = __half22float2(*(__half2*)&r0.w); ac6 += f.x; ac7 += f.y;
        f = __half22float2(*(__half2*)&r1.x); ac0 += f.x; ac1 += f.y;
        f = __half22float2(*(__half2*)&r1.y); ac2 += f.x; ac3 += f.y;
        f = __half22float2(*(__half2*)&r1.z); ac4 += f.x; ac5 += f.y;
        f = __half22float2(*(__half2*)&r1.w); ac6 += f.x; ac7 += f.y;
        f = __half22float2(*(__half2*)&r2.x); ac0 += f.x; ac1 += f.y;
        f = __half22float2(*(__half2*)&r2.y); ac2 += f.x; ac3 += f.y;
        f = __half22float2(*(__half2*)&r2.z); ac4 += f.x; ac5 += f.y;
        f = __half22float2(*(__half2*)&r2.w); ac6 += f.x; ac7 += f.y;
        f = __half22float2(*(__half2*)&r3.x); ac0 += f.x; ac1 += f.y;
        f = __half22float2(*(__half2*)&r3.y); ac2 += f.x; ac3 += f.y;
        f = __half22float2(*(__half2*)&r3.z); ac4 += f.x; ac5 += f.y;
        f = __half22float2(*(__half2*)&r3.w); ac6 += f.x; ac7 += f.y;
    }
    for (; e < end; ++e) {
        int s_ = csr_src[e];
        uint4 r = *(const uint4*)(h1s + (((size_t)s_ << 4) + off));
        float2 f;
        f = __half22float2(*(__half2*)&r.x); ac0 += f.x; ac1 += f.y;
        f = __half22float2(*(__half2*)&r.y); ac2 += f.x; ac3 += f.y;
        f = __half22float2(*(__half2*)&r.z); ac4 += f.x; ac5 += f.y;
        f = __half22float2(*(__half2*)&r.w); ac6 += f.x; ac7 += f.y;
    }
    // self term: + 2*h1s[n]; scale all by dd  (agg = dd*(sum + 2*h1s[n]))
    float val[8];
    {
        uint4 r = *(const uint4*)(h1s + (((size_t)n << 4) + off));
        float2 f;
        f = __half22float2(*(__half2*)&r.x); val[0] = dd * (ac0 + 2.f*f.x); val[1] = dd * (ac1 + 2.f*f.y);
        f = __half22float2(*(__half2*)&r.y); val[2] = dd * (ac2 + 2.f*f.x); val[3] = dd * (ac3 + 2.f*f.y);
        f = __half22float2(*(__half2*)&r.z); val[4] = dd * (ac4 + 2.f*f.x); val[5] = dd * (ac5 + 2.f*f.y);
        f = __half22float2(*(__half2*)&r.w); val[6] = dd * (ac6 + 2.f*f.x); val[7] = dd * (ac7 + 2.f*f.y);
    }
    // exchange with partner lane to build full 16-vector (static indices)
    float pv[8];
    #pragma unroll
    for (int j = 0; j < 8; ++j) pv[j] = __shfl_xor(val[j], 1, 64);
    float av[F1];
    #pragma unroll
    for (int k = 0; k < 8; ++k)  av[k]     = (h == 0) ? val[k] : pv[k];
    #pragma unroll
    for (int k = 0; k < 8; ++k)  av[k + 8] = (h == 0) ? pv[k]  : val[k];

    // h2 slice: thread h computes output columns [16h, 16h+16)
    float hv[16];
    #pragma unroll
    for (int j0 = 0; j0 < 16; ++j0) {
        int j = (h << 4) + j0;
        float acc = sb2[j];
        #pragma unroll
        for (int k = 0; k < F1; ++k) acc += av[k] * sW2[k * F2 + j];
        hv[j0] = fmaxf(acc, 0.0f);
    }

    // wave segmented inclusive scan over 32 node slots (stride-2 lanes), seg = graph
    int g = batch[n];
    #pragma unroll
    for (int d_ = 1; d_ < 32; d_ <<= 1) {
        int sl = lane - (d_ << 1);
        int gs = __shfl(g, sl, 64);
        #pragma unroll
        for (int j0 = 0; j0 < 16; ++j0) {
            float o = __shfl(hv[j0], sl, 64);
            if (islot >= d_ && gs == g) hv[j0] += o;
        }
    }
    int gn = __shfl(g, lane + 2, 64);
    bool endseg = (islot == 31) || (gn != g);
    if (endseg) {
        float* gr = gsum + (size_t)g * F2 + (h << 4);
        #pragma unroll
        for (int j0 = 0; j0 < 16; ++j0) atomicAdd(gr + j0, hv[j0]);
    }
}

// ---------- head ----------
__global__ __launch_bounds__(256) void k_out2(const float* __restrict__ gsum,
                                              const int* __restrict__ gcnt,
                                              const float* __restrict__ Wl,
                                              const float* __restrict__ bl,
                                              float* __restrict__ out) {
    int t = blockIdx.x * 256 + threadIdx.x;
    if (t >= NG * NC) return;
    int g = t / NC, c = t - g * NC;
    float inv = 1.0f / fmaxf((float)gcnt[g], 1.0f);
    const float* gr = gsum + (size_t)g * F2;
    float acc = 0.0f;
    #pragma unroll
    for (int k = 0; k < F2; ++k) acc += gr[k] * Wl[k * NC + c];
    out[t] = acc * inv + bl[c];
}

// ---------------- launcher ----------------
extern "C" void kernel_launch(void* const* d_in, const int* in_sizes, int n_in,
                              void* d_out, int out_size, void* d_ws, size_t ws_size,
                              hipStream_t stream) {
    const float* x    = (const float*)d_in[0];
    const int*   ei   = (const int*)d_in[1];
    const int*   src  = ei;
    const int*   dst  = ei + NE;
    const int*   batch= (const int*)d_in[2];
    const float* W1   = (const float*)d_in[3];
    const float* b1   = (const float*)d_in[4];
    const float* W2   = (const float*)d_in[5];
    const float* b2   = (const float*)d_in[6];
    const float* Wl   = (const float*)d_in[7];
    const float* bl   = (const float*)d_in[8];
    float* out = (float*)d_out;

    // workspace layout — zeroed region first: bcnt, gcnt, gsum
    int*   bcnt    = (int*)d_ws;                     // NB      (zeroed)
    int*   gcnt    = bcnt + NB;                      // NG      (zeroed)
    float* gsum    = (float*)(gcnt + NG);            // 32*NG   (zeroed)
    int*   bbase   = (int*)(gsum + (size_t)F2 * NG); // 257 (+pad 3)
    int*   gcur    = bbase + 260;                    // NB
    int*   rowptr  = gcur + NB;                      // NN+4
    float* dis     = (float*)(rowptr + NN + 4);      // NN
    uint2* xs      = (uint2*)(dis + NN);             // NN uint2 (half4) = 2MB
    int*   csr_src = (int*)(xs + NN);                // NE
    int*   ebuf    = csr_src + NE;                   // NE (aliased with h1s)
    __half* h1s    = (__half*)ebuf;                  // 16*NN halves = 8MB (ebuf dead by k_g1)

    size_t zero_elems = (size_t)NB + NG + (size_t)F2 * NG;
    hipMemsetAsync(d_ws, 0, zero_elems * sizeof(int), stream);

    k_binhist<<<NE / BINCH, 512, 0, stream>>>(dst, bcnt);
    k_bscan  <<<1, 256, 0, stream>>>(bcnt, bbase, gcur);
    k_bin    <<<NE / BINCH, 512, 0, stream>>>(src, dst, gcur, ebuf);
    k_bucket <<<NB, 1024, 0, stream>>>(bbase, ebuf, batch, x, rowptr, csr_src, dis, xs, gcnt);
    k_g1     <<<NN / 256, 256, 0, stream>>>(rowptr, csr_src, dis, xs, W1, b1, h1s);
    k_h2seg  <<<NN * 2 / 256, 256, 0, stream>>>(rowptr, csr_src, dis, h1s, W2, b2, batch, gsum);
    k_out2   <<<(NG * NC + 255) / 256, 256, 0, stream>>>(gsum, gcnt, Wl, bl, out);
}

// Round 8
// 196.099 us; speedup vs baseline: 24.1621x; 1.1292x over previous
//
#include <hip/hip_runtime.h>
#include <hip/hip_fp16.h>

#define NN 262144   // nodes
#define NE 4194304  // edges (divisible by 16384)
#define NG 16384    // graphs
#define NC 26       // classes
#define F1 16
#define F2 32
#define NB 256      // dst buckets (1024 nodes each)
#define BINCH 16384 // edges per binning block

// ---------- bucket histogram: LDS hist -> 256 global atomics/block ----------
__global__ __launch_bounds__(512) void k_binhist(const int* __restrict__ dst,
                                                 int* __restrict__ bcnt) {
    __shared__ int hist[NB];
    int tid = threadIdx.x;
    if (tid < NB) hist[tid] = 0;
    __syncthreads();
    const int4* d4 = (const int4*)(dst + blockIdx.x * BINCH);
    #pragma unroll
    for (int k = 0; k < BINCH / 512 / 4; ++k) {   // 8 iters
        int4 d = d4[tid + k * 512];
        atomicAdd(&hist[d.x >> 10], 1);
        atomicAdd(&hist[d.y >> 10], 1);
        atomicAdd(&hist[d.z >> 10], 1);
        atomicAdd(&hist[d.w >> 10], 1);
    }
    __syncthreads();
    if (tid < NB) atomicAdd(&bcnt[tid], hist[tid]);
}

// ---------- scan bucket counts -> bbase[257]; init gcur ----------
__global__ __launch_bounds__(256) void k_bscan(const int* __restrict__ bcnt,
                                               int* __restrict__ bbase,
                                               int* __restrict__ gcur) {
    __shared__ int s[256];
    int tid = threadIdx.x;
    int v = bcnt[tid];
    s[tid] = v;
    __syncthreads();
    #pragma unroll
    for (int off = 1; off < 256; off <<= 1) {
        int val = (tid >= off) ? s[tid - off] : 0;
        __syncthreads();
        if (tid >= off) s[tid] += val;
        __syncthreads();
    }
    int excl = s[tid] - v;
    bbase[tid] = excl;
    gcur[tid] = excl;
    if (tid == 255) bbase[256] = NE;
}

// ---------- multisplit binning: ebuf bucket-contiguous, packed (src<<10|dl) ----------
__global__ __launch_bounds__(512) void k_bin(const int* __restrict__ src,
                                             const int* __restrict__ dst,
                                             int* __restrict__ gcur,
                                             int* __restrict__ ebuf) {
    __shared__ int hist[NB];
    __shared__ int base[NB];
    int tid = threadIdx.x;
    if (tid < NB) hist[tid] = 0;
    __syncthreads();
    int e0 = blockIdx.x * BINCH;
    const int4* d4 = (const int4*)(dst + e0);
    const int4* s4 = (const int4*)(src + e0);
    #pragma unroll
    for (int k = 0; k < BINCH / 512 / 4; ++k) {   // 8 iters
        int4 d = d4[tid + k * 512];
        atomicAdd(&hist[d.x >> 10], 1);
        atomicAdd(&hist[d.y >> 10], 1);
        atomicAdd(&hist[d.z >> 10], 1);
        atomicAdd(&hist[d.w >> 10], 1);
    }
    __syncthreads();
    if (tid < NB) {
        base[tid] = atomicAdd(&gcur[tid], hist[tid]);
        hist[tid] = 0;
    }
    __syncthreads();
    #pragma unroll
    for (int k = 0; k < BINCH / 512 / 4; ++k) {
        int4 d = d4[tid + k * 512];
        int4 s = s4[tid + k * 512];
        int b, pos;
        b = d.x >> 10; pos = base[b] + atomicAdd(&hist[b], 1); ebuf[pos] = (s.x << 10) | (d.x & 1023);
        b = d.y >> 10; pos = base[b] + atomicAdd(&hist[b], 1); ebuf[pos] = (s.y << 10) | (d.y & 1023);
        b = d.z >> 10; pos = base[b] + atomicAdd(&hist[b], 1); ebuf[pos] = (s.z << 10) | (d.z & 1023);
        b = d.w >> 10; pos = base[b] + atomicAdd(&hist[b], 1); ebuf[pos] = (s.w << 10) | (d.w & 1023);
    }
}

// ---------- per-bucket: LDS degree count + scan -> rowptr/dis/xs/gcnt + scatter ----------
__global__ __launch_bounds__(1024) void k_bucket(const int* __restrict__ bbase,
                                                 const int* __restrict__ ebuf,
                                                 const int* __restrict__ batch,
                                                 const float* __restrict__ x,
                                                 int* __restrict__ rowptr,
                                                 int* __restrict__ csr_src,
                                                 float* __restrict__ dis,
                                                 uint2* __restrict__ xs,
                                                 int* __restrict__ gcnt) {
    __shared__ int sdeg[1024];   // degree, then inclusive scan (in place)
    __shared__ int srow[1024];   // global CSR row start per local node
    __shared__ int scur[1024];   // scatter cursor per local node
    int tid = threadIdx.x;
    int b = blockIdx.x;
    int n0 = b << 10;
    sdeg[tid] = 0;
    __syncthreads();
    int beg = bbase[b], end = bbase[b + 1];
    for (int i = beg + tid; i < end; i += 1024)
        atomicAdd(&sdeg[((unsigned)ebuf[i]) & 1023u], 1);
    __syncthreads();
    int mydeg = sdeg[tid];
    // inclusive Hillis-Steele scan over 1024 elements
    #pragma unroll
    for (int off = 1; off < 1024; off <<= 1) {
        int val = (tid >= off) ? sdeg[tid - off] : 0;
        __syncthreads();
        if (tid >= off) sdeg[tid] += val;
        __syncthreads();
    }
    int row = beg + sdeg[tid] - mydeg;          // exclusive + bucket base
    srow[tid] = row;
    scur[tid] = 0;
    int n = n0 + tid;
    rowptr[n] = row;
    if (b == NB - 1 && tid == 1023) rowptr[NN] = NE;
    float ddn = rsqrtf((float)mydeg + 2.0f);
    dis[n] = ddn;
    // prescaled features xs = dis[n]*x[n], packed half4 (8B)
    float xv0 = x[3 * n], xv1 = x[3 * n + 1], xv2 = x[3 * n + 2];
    __half2 p0 = __floats2half2_rn(ddn * xv0, ddn * xv1);
    __half2 p1 = __floats2half2_rn(ddn * xv2, 0.0f);
    xs[n] = make_uint2(*(unsigned*)&p0, *(unsigned*)&p1);
    atomicAdd(&gcnt[batch[n]], 1);
    __syncthreads();
    for (int i = beg + tid; i < end; i += 1024) {
        unsigned p = (unsigned)ebuf[i];
        int dl = p & 1023u;
        int pos = srow[dl] + atomicAdd(&scur[dl], 1);
        csr_src[pos] = (int)(p >> 10);
    }
}

// ---------- layer 1: gather xs (pure sum) + 3->16 matmul + ReLU -> h1s = dis*h1 (fp16) ----------
__global__ __launch_bounds__(256) void k_g1(const int* __restrict__ rowptr,
                                            const int* __restrict__ csr_src,
                                            const float* __restrict__ dis,
                                            const uint2* __restrict__ xs,
                                            const float* __restrict__ W1,
                                            const float* __restrict__ b1,
                                            __half* __restrict__ h1s) {
    __shared__ float sW1[3 * F1];
    __shared__ float sb1[F1];
    if (threadIdx.x < 3 * F1) sW1[threadIdx.x] = W1[threadIdx.x];
    if (threadIdx.x < F1) sb1[threadIdx.x] = b1[threadIdx.x];
    __syncthreads();
    int n = blockIdx.x * 256 + threadIdx.x;
    float dd = dis[n];
    int beg = rowptr[n], end = rowptr[n + 1];
    float a0 = 0.f, a1v = 0.f, a2 = 0.f;
    int e = beg;
    for (; e + 3 < end; e += 4) {
        int s0 = csr_src[e], s1 = csr_src[e + 1], s2 = csr_src[e + 2], s3 = csr_src[e + 3];
        uint2 r0 = xs[s0], r1 = xs[s1], r2 = xs[s2], r3 = xs[s3];
        float2 l0 = __half22float2(*(__half2*)&r0.x), h0 = __half22float2(*(__half2*)&r0.y);
        float2 l1 = __half22float2(*(__half2*)&r1.x), h1_ = __half22float2(*(__half2*)&r1.y);
        float2 l2 = __half22float2(*(__half2*)&r2.x), h2_ = __half22float2(*(__half2*)&r2.y);
        float2 l3 = __half22float2(*(__half2*)&r3.x), h3_ = __half22float2(*(__half2*)&r3.y);
        a0  += l0.x + l1.x + l2.x + l3.x;
        a1v += l0.y + l1.y + l2.y + l3.y;
        a2  += h0.x + h1_.x + h2_.x + h3_.x;
    }
    for (; e < end; ++e) {
        int s_ = csr_src[e];
        uint2 r = xs[s_];
        float2 lo = __half22float2(*(__half2*)&r.x), hi = __half22float2(*(__half2*)&r.y);
        a0 += lo.x; a1v += lo.y; a2 += hi.x;
    }
    // self term: + 2*xs[n]; whole aggregate scaled by dd
    {
        uint2 rn = xs[n];
        float2 lo = __half22float2(*(__half2*)&rn.x), hi = __half22float2(*(__half2*)&rn.y);
        a0 += 2.0f * lo.x; a1v += 2.0f * lo.y; a2 += 2.0f * hi.x;
    }
    float g0 = dd * a0, g1 = dd * a1v, g2 = dd * a2;
    float vals[F1];
    #pragma unroll
    for (int col = 0; col < F1; ++col) {
        float acc = sb1[col];
        acc += g0 * sW1[0 * F1 + col];
        acc += g1 * sW1[1 * F1 + col];
        acc += g2 * sW1[2 * F1 + col];
        vals[col] = dd * fmaxf(acc, 0.0f);    // h1s = dis[n] * relu(...)
    }
    unsigned u[8];
    #pragma unroll
    for (int p = 0; p < 8; ++p) {
        __half2 hp = __floats2half2_rn(vals[2 * p], vals[2 * p + 1]);
        u[p] = *(unsigned*)&hp;
    }
    uint4* hr = (uint4*)(h1s + ((size_t)n << 4));
    hr[0] = make_uint4(u[0], u[1], u[2], u[3]);
    hr[1] = make_uint4(u[4], u[5], u[6], u[7]);
}

// ---------- layer 2: 4 threads/node, 8B gathers of prescaled h1s (pure sum)
// + quad-shuffle assembly + fused 16->32 matmul + ReLU + seg-scan pooling ----------
__global__ __launch_bounds__(256) void k_h2seg(const int* __restrict__ rowptr,
                                               const int* __restrict__ csr_src,
                                               const float* __restrict__ dis,
                                               const __half* __restrict__ h1s,
                                               const float* __restrict__ W2,
                                               const float* __restrict__ b2,
                                               const int* __restrict__ batch,
                                               float* __restrict__ gsum) {
    __shared__ float sW2[F1 * F2];
    __shared__ float sb2[F2];
    for (int i = threadIdx.x; i < F1 * F2; i += 256) sW2[i] = W2[i];
    if (threadIdx.x < F2) sb2[threadIdx.x] = b2[threadIdx.x];
    __syncthreads();
    int t = blockIdx.x * 256 + threadIdx.x;   // grid exact: t < 4*NN
    int n = t >> 2;                           // node
    int q = t & 3;                            // feature quad (4 halves = 8B)
    int lane = threadIdx.x & 63;
    int islot = lane >> 2;                    // node slot within wave (0..15)
    float dd = dis[n];
    int beg = rowptr[n], end = rowptr[n + 1];
    float ax = 0.f, ay = 0.f, az = 0.f, aw = 0.f;
    int qoff = q << 2;
    int e = beg;
    // 8-edge unroll: 8 idx + 8x8B loads in flight
    for (; e + 7 < end; e += 8) {
        int s0 = csr_src[e],   s1 = csr_src[e+1], s2 = csr_src[e+2], s3 = csr_src[e+3];
        int s4 = csr_src[e+4], s5 = csr_src[e+5], s6 = csr_src[e+6], s7 = csr_src[e+7];
        uint2 r0 = *(const uint2*)(h1s + (((size_t)s0 << 4) + qoff));
        uint2 r1 = *(const uint2*)(h1s + (((size_t)s1 << 4) + qoff));
        uint2 r2 = *(const uint2*)(h1s + (((size_t)s2 << 4) + qoff));
        uint2 r3 = *(const uint2*)(h1s + (((size_t)s3 << 4) + qoff));
        uint2 r4 = *(const uint2*)(h1s + (((size_t)s4 << 4) + qoff));
        uint2 r5 = *(const uint2*)(h1s + (((size_t)s5 << 4) + qoff));
        uint2 r6 = *(const uint2*)(h1s + (((size_t)s6 << 4) + qoff));
        uint2 r7 = *(const uint2*)(h1s + (((size_t)s7 << 4) + qoff));
        float2 f;
        f = __half22float2(*(__half2*)&r0.x); ax += f.x; ay += f.y;
        f = __half22float2(*(__half2*)&r0.y); az += f.x; aw += f.y;
        f = __half22float2(*(__half2*)&r1.x); ax += f.x; ay += f.y;
        f = __half22float2(*(__half2*)&r1.y); az += f.x; aw += f.y;
        f = __half22float2(*(__half2*)&r2.x); ax += f.x; ay += f.y;
        f = __half22float2(*(__half2*)&r2.y); az += f.x; aw += f.y;
        f = __half22float2(*(__half2*)&r3.x); ax += f.x; ay += f.y;
        f = __half22float2(*(__half2*)&r3.y); az += f.x; aw += f.y;
        f = __half22float2(*(__half2*)&r4.x); ax += f.x; ay += f.y;
        f = __half22float2(*(__half2*)&r4.y); az += f.x; aw += f.y;
        f = __half22float2(*(__half2*)&r5.x); ax += f.x; ay += f.y;
        f = __half22float2(*(__half2*)&r5.y); az += f.x; aw += f.y;
        f = __half22float2(*(__half2*)&r6.x); ax += f.x; ay += f.y;
        f = __half22float2(*(__half2*)&r6.y); az += f.x; aw += f.y;
        f = __half22float2(*(__half2*)&r7.x); ax += f.x; ay += f.y;
        f = __half22float2(*(__half2*)&r7.y); az += f.x; aw += f.y;
    }
    for (; e + 3 < end; e += 4) {
        int s0 = csr_src[e], s1 = csr_src[e+1], s2 = csr_src[e+2], s3 = csr_src[e+3];
        uint2 r0 = *(const uint2*)(h1s + (((size_t)s0 << 4) + qoff));
        uint2 r1 = *(const uint2*)(h1s + (((size_t)s1 << 4) + qoff));
        uint2 r2 = *(const uint2*)(h1s + (((size_t)s2 << 4) + qoff));
        uint2 r3 = *(const uint2*)(h1s + (((size_t)s3 << 4) + qoff));
        float2 f;
        f = __half22float2(*(__half2*)&r0.x); ax += f.x; ay += f.y;
        f = __half22float2(*(__half2*)&r0.y); az += f.x; aw += f.y;
        f = __half22float2(*(__half2*)&r1.x); ax += f.x; ay += f.y;
        f = __half22float2(*(__half2*)&r1.y); az += f.x; aw += f.y;
        f = __half22float2(*(__half2*)&r2.x); ax += f.x; ay += f.y;
        f = __half22float2(*(__half2*)&r2.y); az += f.x; aw += f.y;
        f = __half22float2(*(__half2*)&r3.x); ax += f.x; ay += f.y;
        f = __half22float2(*(__half2*)&r3.y); az += f.x; aw += f.y;
    }
    for (; e < end; ++e) {
        int s_ = csr_src[e];
        uint2 r = *(const uint2*)(h1s + (((size_t)s_ << 4) + qoff));
        float2 f;
        f = __half22float2(*(__half2*)&r.x); ax += f.x; ay += f.y;
        f = __half22float2(*(__half2*)&r.y); az += f.x; aw += f.y;
    }
    // self term + scale: agg = dd*(sum + 2*h1s[n])
    {
        uint2 r = *(const uint2*)(h1s + (((size_t)n << 4) + qoff));
        float2 fa = __half22float2(*(__half2*)&r.x), fb = __half22float2(*(__half2*)&r.y);
        ax = dd * (ax + 2.f * fa.x); ay = dd * (ay + 2.f * fa.y);
        az = dd * (az + 2.f * fb.x); aw = dd * (aw + 2.f * fb.y);
    }

    // assemble full 16-vector in each lane of the quad
    int qbase = lane & ~3;
    float av[F1];
    #pragma unroll
    for (int k = 0; k < F1; ++k) {
        int kc = k & 3;
        float comp = (kc == 0) ? ax : (kc == 1) ? ay : (kc == 2) ? az : aw;
        av[k] = __shfl(comp, qbase + (k >> 2), 64);
    }

    // h2 slice: thread q computes output columns [8q, 8q+8)
    float hv[8];
    #pragma unroll
    for (int j0 = 0; j0 < 8; ++j0) {
        int j = q * 8 + j0;
        float acc = sb2[j];
        #pragma unroll
        for (int k = 0; k < F1; ++k) acc += av[k] * sW2[k * F2 + j];
        hv[j0] = fmaxf(acc, 0.0f);
    }

    // wave segmented inclusive scan over node slots (stride-4 lanes), seg = graph
    int g = batch[n];
    #pragma unroll
    for (int d_ = 1; d_ < 16; d_ <<= 1) {
        int sl = lane - 4 * d_;
        int gs = __shfl(g, sl, 64);
        #pragma unroll
        for (int j0 = 0; j0 < 8; ++j0) {
            float o = __shfl(hv[j0], sl, 64);
            if (islot >= d_ && gs == g) hv[j0] += o;
        }
    }
    int gn = __shfl(g, lane + 4, 64);
    bool endseg = (islot == 15) || (gn != g);
    if (endseg) {
        float* gr = gsum + (size_t)g * F2 + q * 8;
        #pragma unroll
        for (int j0 = 0; j0 < 8; ++j0) atomicAdd(gr + j0, hv[j0]);
    }
}

// ---------- head ----------
__global__ __launch_bounds__(256) void k_out2(const float* __restrict__ gsum,
                                              const int* __restrict__ gcnt,
                                              const float* __restrict__ Wl,
                                              const float* __restrict__ bl,
                                              float* __restrict__ out) {
    int t = blockIdx.x * 256 + threadIdx.x;
    if (t >= NG * NC) return;
    int g = t / NC, c = t - g * NC;
    float inv = 1.0f / fmaxf((float)gcnt[g], 1.0f);
    const float* gr = gsum + (size_t)g * F2;
    float acc = 0.0f;
    #pragma unroll
    for (int k = 0; k < F2; ++k) acc += gr[k] * Wl[k * NC + c];
    out[t] = acc * inv + bl[c];
}

// ---------------- launcher ----------------
extern "C" void kernel_launch(void* const* d_in, const int* in_sizes, int n_in,
                              void* d_out, int out_size, void* d_ws, size_t ws_size,
                              hipStream_t stream) {
    const float* x    = (const float*)d_in[0];
    const int*   ei   = (const int*)d_in[1];
    const int*   src  = ei;
    const int*   dst  = ei + NE;
    const int*   batch= (const int*)d_in[2];
    const float* W1   = (const float*)d_in[3];
    const float* b1   = (const float*)d_in[4];
    const float* W2   = (const float*)d_in[5];
    const float* b2   = (const float*)d_in[6];
    const float* Wl   = (const float*)d_in[7];
    const float* bl   = (const float*)d_in[8];
    float* out = (float*)d_out;

    // workspace layout — zeroed region first: bcnt, gcnt, gsum
    int*   bcnt    = (int*)d_ws;                     // NB      (zeroed)
    int*   gcnt    = bcnt + NB;                      // NG      (zeroed)
    float* gsum    = (float*)(gcnt + NG);            // 32*NG   (zeroed)
    int*   bbase   = (int*)(gsum + (size_t)F2 * NG); // 257 (+pad 3)
    int*   gcur    = bbase + 260;                    // NB
    int*   rowptr  = gcur + NB;                      // NN+4
    float* dis     = (float*)(rowptr + NN + 4);      // NN
    uint2* xs      = (uint2*)(dis + NN);             // NN uint2 (half4) = 2MB
    int*   csr_src = (int*)(xs + NN);                // NE
    int*   ebuf    = csr_src + NE;                   // NE (aliased with h1s)
    __half* h1s    = (__half*)ebuf;                  // 16*NN halves = 8MB (ebuf dead by k_g1)

    size_t zero_elems = (size_t)NB + NG + (size_t)F2 * NG;
    hipMemsetAsync(d_ws, 0, zero_elems * sizeof(int), stream);

    k_binhist<<<NE / BINCH, 512, 0, stream>>>(dst, bcnt);
    k_bscan  <<<1, 256, 0, stream>>>(bcnt, bbase, gcur);
    k_bin    <<<NE / BINCH, 512, 0, stream>>>(src, dst, gcur, ebuf);
    k_bucket <<<NB, 1024, 0, stream>>>(bbase, ebuf, batch, x, rowptr, csr_src, dis, xs, gcnt);
    k_g1     <<<NN / 256, 256, 0, stream>>>(rowptr, csr_src, dis, xs, W1, b1, h1s);
    k_h2seg  <<<NN * 4 / 256, 256, 0, stream>>>(rowptr, csr_src, dis, h1s, W2, b2, batch, gsum);
    k_out2   <<<(NG * NC + 255) / 256, 256, 0, stream>>>(gsum, gcnt, Wl, bl, out);
}

// Round 9
// 192.788 us; speedup vs baseline: 24.5771x; 1.0172x over previous
//
#include <hip/hip_runtime.h>
#include <hip/hip_fp16.h>

#define NN 262144   // nodes
#define NE 4194304  // edges (divisible by 16384)
#define NG 16384    // graphs
#define NC 26       // classes
#define F1 16
#define F2 32
#define NB 256      // dst buckets (1024 nodes each)
#define BINCH 16384 // edges per binning block
#define KMAX 18     // max edges per thread in k_bucket (18*1024=18432 >= max bucket size)

// ---------- bucket histogram: LDS hist -> 256 global atomics/block ----------
__global__ __launch_bounds__(512) void k_binhist(const int* __restrict__ dst,
                                                 int* __restrict__ bcnt) {
    __shared__ int hist[NB];
    int tid = threadIdx.x;
    if (tid < NB) hist[tid] = 0;
    __syncthreads();
    const int4* d4 = (const int4*)(dst + blockIdx.x * BINCH);
    #pragma unroll
    for (int k = 0; k < BINCH / 512 / 4; ++k) {   // 8 iters
        int4 d = d4[tid + k * 512];
        atomicAdd(&hist[d.x >> 10], 1);
        atomicAdd(&hist[d.y >> 10], 1);
        atomicAdd(&hist[d.z >> 10], 1);
        atomicAdd(&hist[d.w >> 10], 1);
    }
    __syncthreads();
    if (tid < NB) atomicAdd(&bcnt[tid], hist[tid]);
}

// ---------- scan bucket counts -> bbase[257]; init gcur ----------
__global__ __launch_bounds__(256) void k_bscan(const int* __restrict__ bcnt,
                                               int* __restrict__ bbase,
                                               int* __restrict__ gcur) {
    __shared__ int s[256];
    int tid = threadIdx.x;
    int v = bcnt[tid];
    s[tid] = v;
    __syncthreads();
    #pragma unroll
    for (int off = 1; off < 256; off <<= 1) {
        int val = (tid >= off) ? s[tid - off] : 0;
        __syncthreads();
        if (tid >= off) s[tid] += val;
        __syncthreads();
    }
    int excl = s[tid] - v;
    bbase[tid] = excl;
    gcur[tid] = excl;
    if (tid == 255) bbase[256] = NE;
}

// ---------- multisplit binning: ebuf bucket-contiguous, packed (src<<10|dl) ----------
__global__ __launch_bounds__(512) void k_bin(const int* __restrict__ src,
                                             const int* __restrict__ dst,
                                             int* __restrict__ gcur,
                                             int* __restrict__ ebuf) {
    __shared__ int hist[NB];
    __shared__ int base[NB];
    int tid = threadIdx.x;
    if (tid < NB) hist[tid] = 0;
    __syncthreads();
    int e0 = blockIdx.x * BINCH;
    const int4* d4 = (const int4*)(dst + e0);
    const int4* s4 = (const int4*)(src + e0);
    #pragma unroll
    for (int k = 0; k < BINCH / 512 / 4; ++k) {   // 8 iters
        int4 d = d4[tid + k * 512];
        atomicAdd(&hist[d.x >> 10], 1);
        atomicAdd(&hist[d.y >> 10], 1);
        atomicAdd(&hist[d.z >> 10], 1);
        atomicAdd(&hist[d.w >> 10], 1);
    }
    __syncthreads();
    if (tid < NB) {
        base[tid] = atomicAdd(&gcur[tid], hist[tid]);
        hist[tid] = 0;
    }
    __syncthreads();
    #pragma unroll
    for (int k = 0; k < BINCH / 512 / 4; ++k) {
        int4 d = d4[tid + k * 512];
        int4 s = s4[tid + k * 512];
        int b, pos;
        b = d.x >> 10; pos = base[b] + atomicAdd(&hist[b], 1); ebuf[pos] = (s.x << 10) | (d.x & 1023);
        b = d.y >> 10; pos = base[b] + atomicAdd(&hist[b], 1); ebuf[pos] = (s.y << 10) | (d.y & 1023);
        b = d.z >> 10; pos = base[b] + atomicAdd(&hist[b], 1); ebuf[pos] = (s.z << 10) | (d.z & 1023);
        b = d.w >> 10; pos = base[b] + atomicAdd(&hist[b], 1); ebuf[pos] = (s.w << 10) | (d.w & 1023);
    }
}

// ---------- per-bucket: reg-preload ebuf (single read) + LDS deg hist +
// wave-level scan (2 barriers) -> rowptr/dis/xs/gcnt + reg scatter ----------
__global__ __launch_bounds__(1024) void k_bucket(const int* __restrict__ bbase,
                                                 const int* __restrict__ ebuf,
                                                 const int* __restrict__ batch,
                                                 const float* __restrict__ x,
                                                 int* __restrict__ rowptr,
                                                 int* __restrict__ csr_src,
                                                 float* __restrict__ dis,
                                                 uint2* __restrict__ xs,
                                                 int* __restrict__ gcnt) {
    __shared__ int sdeg[1024];   // degree counters
    __shared__ int srow[1024];   // global CSR row start per local node
    __shared__ int scur[1024];   // scatter cursor per local node
    __shared__ int wsum[16];     // per-wave scan sums
    int tid = threadIdx.x;
    int lane = tid & 63;
    int wid = tid >> 6;
    int b = blockIdx.x;
    int n0 = b << 10;
    sdeg[tid] = 0;
    scur[tid] = 0;
    __syncthreads();
    int beg = bbase[b], end = bbase[b + 1];
    // preload this thread's edges into registers (single ebuf read)
    int ev[KMAX];
    #pragma unroll
    for (int k = 0; k < KMAX; ++k) {
        int i = beg + tid + (k << 10);
        ev[k] = (i < end) ? ebuf[i] : -1;
    }
    // degree histogram from registers
    #pragma unroll
    for (int k = 0; k < KMAX; ++k)
        if (ev[k] >= 0) atomicAdd(&sdeg[((unsigned)ev[k]) & 1023u], 1);
    __syncthreads();
    int mydeg = sdeg[tid];
    // wave inclusive scan (shfl), then combine 16 wave sums in LDS
    int incl = mydeg;
    #pragma unroll
    for (int off = 1; off < 64; off <<= 1) {
        int v = __shfl_up(incl, off, 64);
        if (lane >= off) incl += v;
    }
    if (lane == 63) wsum[wid] = incl;
    __syncthreads();
    if (wid == 0) {
        int v = (lane < 16) ? wsum[lane] : 0;
        int s = v;
        #pragma unroll
        for (int off = 1; off < 16; off <<= 1) {
            int u = __shfl_up(s, off, 64);
            if (lane >= off) s += u;
        }
        if (lane < 16) wsum[lane] = s - v;   // exclusive wave base
    }
    __syncthreads();
    int row = beg + wsum[wid] + incl - mydeg;   // global CSR start for node n
    srow[tid] = row;
    int n = n0 + tid;
    rowptr[n] = row;
    if (b == NB - 1 && tid == 1023) rowptr[NN] = NE;
    float ddn = rsqrtf((float)mydeg + 2.0f);
    dis[n] = ddn;
    // prescaled features xs = dis[n]*x[n], packed half4 (8B)
    float xv0 = x[3 * n], xv1 = x[3 * n + 1], xv2 = x[3 * n + 2];
    __half2 p0 = __floats2half2_rn(ddn * xv0, ddn * xv1);
    __half2 p1 = __floats2half2_rn(ddn * xv2, 0.0f);
    xs[n] = make_uint2(*(unsigned*)&p0, *(unsigned*)&p1);
    atomicAdd(&gcnt[batch[n]], 1);
    __syncthreads();
    // scatter from registers
    #pragma unroll
    for (int k = 0; k < KMAX; ++k) {
        if (ev[k] >= 0) {
            unsigned p = (unsigned)ev[k];
            int dl = p & 1023u;
            int pos = srow[dl] + atomicAdd(&scur[dl], 1);
            csr_src[pos] = (int)(p >> 10);
        }
    }
}

// ---------- layer 1: gather xs (pure sum, 8x unroll) + 3->16 matmul + ReLU -> h1s ----------
__global__ __launch_bounds__(256) void k_g1(const int* __restrict__ rowptr,
                                            const int* __restrict__ csr_src,
                                            const float* __restrict__ dis,
                                            const uint2* __restrict__ xs,
                                            const float* __restrict__ W1,
                                            const float* __restrict__ b1,
                                            __half* __restrict__ h1s) {
    __shared__ float sW1[3 * F1];
    __shared__ float sb1[F1];
    if (threadIdx.x < 3 * F1) sW1[threadIdx.x] = W1[threadIdx.x];
    if (threadIdx.x < F1) sb1[threadIdx.x] = b1[threadIdx.x];
    __syncthreads();
    int n = blockIdx.x * 256 + threadIdx.x;
    float dd = dis[n];
    int beg = rowptr[n], end = rowptr[n + 1];
    float a0 = 0.f, a1v = 0.f, a2 = 0.f;
    int e = beg;
    for (; e + 7 < end; e += 8) {
        int s0 = csr_src[e],   s1 = csr_src[e+1], s2 = csr_src[e+2], s3 = csr_src[e+3];
        int s4 = csr_src[e+4], s5 = csr_src[e+5], s6 = csr_src[e+6], s7 = csr_src[e+7];
        uint2 r0 = xs[s0], r1 = xs[s1], r2 = xs[s2], r3 = xs[s3];
        uint2 r4 = xs[s4], r5 = xs[s5], r6 = xs[s6], r7 = xs[s7];
        float2 f;
        f = __half22float2(*(__half2*)&r0.x); a0 += f.x; a1v += f.y;
        f = __half22float2(*(__half2*)&r0.y); a2 += f.x;
        f = __half22float2(*(__half2*)&r1.x); a0 += f.x; a1v += f.y;
        f = __half22float2(*(__half2*)&r1.y); a2 += f.x;
        f = __half22float2(*(__half2*)&r2.x); a0 += f.x; a1v += f.y;
        f = __half22float2(*(__half2*)&r2.y); a2 += f.x;
        f = __half22float2(*(__half2*)&r3.x); a0 += f.x; a1v += f.y;
        f = __half22float2(*(__half2*)&r3.y); a2 += f.x;
        f = __half22float2(*(__half2*)&r4.x); a0 += f.x; a1v += f.y;
        f = __half22float2(*(__half2*)&r4.y); a2 += f.x;
        f = __half22float2(*(__half2*)&r5.x); a0 += f.x; a1v += f.y;
        f = __half22float2(*(__half2*)&r5.y); a2 += f.x;
        f = __half22float2(*(__half2*)&r6.x); a0 += f.x; a1v += f.y;
        f = __half22float2(*(__half2*)&r6.y); a2 += f.x;
        f = __half22float2(*(__half2*)&r7.x); a0 += f.x; a1v += f.y;
        f = __half22float2(*(__half2*)&r7.y); a2 += f.x;
    }
    for (; e < end; ++e) {
        int s_ = csr_src[e];
        uint2 r = xs[s_];
        float2 lo = __half22float2(*(__half2*)&r.x), hi = __half22float2(*(__half2*)&r.y);
        a0 += lo.x; a1v += lo.y; a2 += hi.x;
    }
    // self term: + 2*xs[n]; whole aggregate scaled by dd
    {
        uint2 rn = xs[n];
        float2 lo = __half22float2(*(__half2*)&rn.x), hi = __half22float2(*(__half2*)&rn.y);
        a0 += 2.0f * lo.x; a1v += 2.0f * lo.y; a2 += 2.0f * hi.x;
    }
    float g0 = dd * a0, g1 = dd * a1v, g2 = dd * a2;
    float vals[F1];
    #pragma unroll
    for (int col = 0; col < F1; ++col) {
        float acc = sb1[col];
        acc += g0 * sW1[0 * F1 + col];
        acc += g1 * sW1[1 * F1 + col];
        acc += g2 * sW1[2 * F1 + col];
        vals[col] = dd * fmaxf(acc, 0.0f);    // h1s = dis[n] * relu(...)
    }
    unsigned u[8];
    #pragma unroll
    for (int p = 0; p < 8; ++p) {
        __half2 hp = __floats2half2_rn(vals[2 * p], vals[2 * p + 1]);
        u[p] = *(unsigned*)&hp;
    }
    uint4* hr = (uint4*)(h1s + ((size_t)n << 4));
    hr[0] = make_uint4(u[0], u[1], u[2], u[3]);
    hr[1] = make_uint4(u[4], u[5], u[6], u[7]);
}

// ---------- layer 2: 4 threads/node, 8B gathers, 16-edge unroll
// + quad-shuffle assembly + fused 16->32 matmul + ReLU + seg-scan pooling ----------
__global__ __launch_bounds__(256) void k_h2seg(const int* __restrict__ rowptr,
                                               const int* __restrict__ csr_src,
                                               const float* __restrict__ dis,
                                               const __half* __restrict__ h1s,
                                               const float* __restrict__ W2,
                                               const float* __restrict__ b2,
                                               const int* __restrict__ batch,
                                               float* __restrict__ gsum) {
    __shared__ float sW2[F1 * F2];
    __shared__ float sb2[F2];
    for (int i = threadIdx.x; i < F1 * F2; i += 256) sW2[i] = W2[i];
    if (threadIdx.x < F2) sb2[threadIdx.x] = b2[threadIdx.x];
    __syncthreads();
    int t = blockIdx.x * 256 + threadIdx.x;   // grid exact: t < 4*NN
    int n = t >> 2;                           // node
    int q = t & 3;                            // feature quad (4 halves = 8B)
    int lane = threadIdx.x & 63;
    int islot = lane >> 2;                    // node slot within wave (0..15)
    float dd = dis[n];
    int beg = rowptr[n], end = rowptr[n + 1];
    float ax = 0.f, ay = 0.f, az = 0.f, aw = 0.f;
    int qoff = q << 2;
    int e = beg;
    // 16-edge unroll: 16 idx + 16x8B gathers in flight
    for (; e + 15 < end; e += 16) {
        int si[16];
        #pragma unroll
        for (int k = 0; k < 16; ++k) si[k] = csr_src[e + k];
        uint2 rr[16];
        #pragma unroll
        for (int k = 0; k < 16; ++k)
            rr[k] = *(const uint2*)(h1s + (((size_t)si[k] << 4) + qoff));
        #pragma unroll
        for (int k = 0; k < 16; ++k) {
            float2 f;
            f = __half22float2(*(__half2*)&rr[k].x); ax += f.x; ay += f.y;
            f = __half22float2(*(__half2*)&rr[k].y); az += f.x; aw += f.y;
        }
    }
    for (; e + 3 < end; e += 4) {
        int s0 = csr_src[e], s1 = csr_src[e+1], s2 = csr_src[e+2], s3 = csr_src[e+3];
        uint2 r0 = *(const uint2*)(h1s + (((size_t)s0 << 4) + qoff));
        uint2 r1 = *(const uint2*)(h1s + (((size_t)s1 << 4) + qoff));
        uint2 r2 = *(const uint2*)(h1s + (((size_t)s2 << 4) + qoff));
        uint2 r3 = *(const uint2*)(h1s + (((size_t)s3 << 4) + qoff));
        float2 f;
        f = __half22float2(*(__half2*)&r0.x); ax += f.x; ay += f.y;
        f = __half22float2(*(__half2*)&r0.y); az += f.x; aw += f.y;
        f = __half22float2(*(__half2*)&r1.x); ax += f.x; ay += f.y;
        f = __half22float2(*(__half2*)&r1.y); az += f.x; aw += f.y;
        f = __half22float2(*(__half2*)&r2.x); ax += f.x; ay += f.y;
        f = __half22float2(*(__half2*)&r2.y); az += f.x; aw += f.y;
        f = __half22float2(*(__half2*)&r3.x); ax += f.x; ay += f.y;
        f = __half22float2(*(__half2*)&r3.y); az += f.x; aw += f.y;
    }
    for (; e < end; ++e) {
        int s_ = csr_src[e];
        uint2 r = *(const uint2*)(h1s + (((size_t)s_ << 4) + qoff));
        float2 f;
        f = __half22float2(*(__half2*)&r.x); ax += f.x; ay += f.y;
        f = __half22float2(*(__half2*)&r.y); az += f.x; aw += f.y;
    }
    // self term + scale: agg = dd*(sum + 2*h1s[n])
    {
        uint2 r = *(const uint2*)(h1s + (((size_t)n << 4) + qoff));
        float2 fa = __half22float2(*(__half2*)&r.x), fb = __half22float2(*(__half2*)&r.y);
        ax = dd * (ax + 2.f * fa.x); ay = dd * (ay + 2.f * fa.y);
        az = dd * (az + 2.f * fb.x); aw = dd * (aw + 2.f * fb.y);
    }

    // assemble full 16-vector in each lane of the quad
    int qbase = lane & ~3;
    float av[F1];
    #pragma unroll
    for (int k = 0; k < F1; ++k) {
        int kc = k & 3;
        float comp = (kc == 0) ? ax : (kc == 1) ? ay : (kc == 2) ? az : aw;
        av[k] = __shfl(comp, qbase + (k >> 2), 64);
    }

    // h2 slice: thread q computes output columns [8q, 8q+8)
    float hv[8];
    #pragma unroll
    for (int j0 = 0; j0 < 8; ++j0) {
        int j = q * 8 + j0;
        float acc = sb2[j];
        #pragma unroll
        for (int k = 0; k < F1; ++k) acc += av[k] * sW2[k * F2 + j];
        hv[j0] = fmaxf(acc, 0.0f);
    }

    // wave segmented inclusive scan over node slots (stride-4 lanes), seg = graph
    int g = batch[n];
    #pragma unroll
    for (int d_ = 1; d_ < 16; d_ <<= 1) {
        int sl = lane - 4 * d_;
        int gs = __shfl(g, sl, 64);
        #pragma unroll
        for (int j0 = 0; j0 < 8; ++j0) {
            float o = __shfl(hv[j0], sl, 64);
            if (islot >= d_ && gs == g) hv[j0] += o;
        }
    }
    int gn = __shfl(g, lane + 4, 64);
    bool endseg = (islot == 15) || (gn != g);
    if (endseg) {
        float* gr = gsum + (size_t)g * F2 + q * 8;
        #pragma unroll
        for (int j0 = 0; j0 < 8; ++j0) atomicAdd(gr + j0, hv[j0]);
    }
}

// ---------- head ----------
__global__ __launch_bounds__(256) void k_out2(const float* __restrict__ gsum,
                                              const int* __restrict__ gcnt,
                                              const float* __restrict__ Wl,
                                              const float* __restrict__ bl,
                                              float* __restrict__ out) {
    int t = blockIdx.x * 256 + threadIdx.x;
    if (t >= NG * NC) return;
    int g = t / NC, c = t - g * NC;
    float inv = 1.0f / fmaxf((float)gcnt[g], 1.0f);
    const float* gr = gsum + (size_t)g * F2;
    float acc = 0.0f;
    #pragma unroll
    for (int k = 0; k < F2; ++k) acc += gr[k] * Wl[k * NC + c];
    out[t] = acc * inv + bl[c];
}

// ---------------- launcher ----------------
extern "C" void kernel_launch(void* const* d_in, const int* in_sizes, int n_in,
                              void* d_out, int out_size, void* d_ws, size_t ws_size,
                              hipStream_t stream) {
    const float* x    = (const float*)d_in[0];
    const int*   ei   = (const int*)d_in[1];
    const int*   src  = ei;
    const int*   dst  = ei + NE;
    const int*   batch= (const int*)d_in[2];
    const float* W1   = (const float*)d_in[3];
    const float* b1   = (const float*)d_in[4];
    const float* W2   = (const float*)d_in[5];
    const float* b2   = (const float*)d_in[6];
    const float* Wl   = (const float*)d_in[7];
    const float* bl   = (const float*)d_in[8];
    float* out = (float*)d_out;

    // workspace layout — zeroed region first: bcnt, gcnt, gsum
    int*   bcnt    = (int*)d_ws;                     // NB      (zeroed)
    int*   gcnt    = bcnt + NB;                      // NG      (zeroed)
    float* gsum    = (float*)(gcnt + NG);            // 32*NG   (zeroed)
    int*   bbase   = (int*)(gsum + (size_t)F2 * NG); // 257 (+pad 3)
    int*   gcur    = bbase + 260;                    // NB
    int*   rowptr  = gcur + NB;                      // NN+4
    float* dis     = (float*)(rowptr + NN + 4);      // NN
    uint2* xs      = (uint2*)(dis + NN);             // NN uint2 (half4) = 2MB
    int*   csr_src = (int*)(xs + NN);                // NE
    int*   ebuf    = csr_src + NE;                   // NE (aliased with h1s)
    __half* h1s    = (__half*)ebuf;                  // 16*NN halves = 8MB (ebuf dead by k_g1)

    size_t zero_elems = (size_t)NB + NG + (size_t)F2 * NG;
    hipMemsetAsync(d_ws, 0, zero_elems * sizeof(int), stream);

    k_binhist<<<NE / BINCH, 512, 0, stream>>>(dst, bcnt);
    k_bscan  <<<1, 256, 0, stream>>>(bcnt, bbase, gcur);
    k_bin    <<<NE / BINCH, 512, 0, stream>>>(src, dst, gcur, ebuf);
    k_bucket <<<NB, 1024, 0, stream>>>(bbase, ebuf, batch, x, rowptr, csr_src, dis, xs, gcnt);
    k_g1     <<<NN / 256, 256, 0, stream>>>(rowptr, csr_src, dis, xs, W1, b1, h1s);
    k_h2seg  <<<NN * 4 / 256, 256, 0, stream>>>(rowptr, csr_src, dis, h1s, W2, b2, batch, gsum);
    k_out2   <<<(NG * NC + 255) / 256, 256, 0, stream>>>(gsum, gcnt, Wl, bl, out);
}